// Round 6
// baseline (195.624 us; speedup 1.0000x reference)
//
#include <hip/hip_runtime.h>

#define NB 2048
#define CNT 32768.0f   // per-channel count = B*H*W = 2048*16

// workspace float offsets
#define OFF_Y1   0          // 2048*32*16
#define OFF_Y2   1048576    // 2048*64*16
#define OFF_Y3   3145728    // 2048*128*16
#define OFF_Y4   7340032    // 2048*128*16
#define OFF_ST   11534336   // 4 layers x 256
#define OFF_W2P  11536384   // conv2 pack: 18432 ushort
#define OFF_W3P  11545600   // conv3 pack: 73728 ushort
#define OFF_WPP  11582464   // offset-conv pack: 36864 ushort
#define OFF_WDP  11600896   // Wd pack: 147456 ushort

typedef __attribute__((ext_vector_type(8))) short bf16x8;
typedef __attribute__((ext_vector_type(4))) float f32x4;

__device__ __forceinline__ unsigned short f2bf(float f) {
  union { float f; unsigned int u; } v; v.f = f;
  unsigned int r = v.u + 0x7FFFu + ((v.u >> 16) & 1u);
  return (unsigned short)(r >> 16);
}

// pack conv weight [CO][CI][3][3] -> bf16 B-fragments, tap-major K (step = tap*KST+ks)
__device__ __forceinline__ void packw_one(const float* __restrict__ w, unsigned short* __restrict__ wpk,
                                          int CI, int CO, int NT, int i) {
  int KST = CI >> 5;
  int j = i & 7, l = (i >> 3) & 63, sn = i >> 9;
  int nt = sn % NT, step = sn / NT;
  int tap = step / KST, ks = step - tap * KST;
  int ci = ks * 32 + (l >> 4) * 8 + j, co = nt * 16 + (l & 15);
  wpk[i] = (co < CO) ? f2bf(w[(co * CI + ci) * 9 + tap]) : (unsigned short)0;
}

// pack Wd: K order k = ci*9 + tap (verified)
__device__ __forceinline__ void packwd_one(const float* __restrict__ Wd, unsigned short* __restrict__ wdp, int i) {
  int co = i / 1152, k = i % 1152;
  int t = k >> 5, kk = k & 31, g = kk >> 3, j = kk & 7;
  int nt = co >> 4, cc = co & 15, l = g * 16 + cc;
  wdp[((t * 8 + nt) * 64 + l) * 8 + j] = f2bf(Wd[i]);
}

// merged: blocks [0,1080) pack weights; blocks [1080,3128) run conv1 (3->32, fp32)
__global__ __launch_bounds__(256) void k_pre(const float* __restrict__ W2, const float* __restrict__ W3,
                                             const float* __restrict__ Wp, const float* __restrict__ Wd,
                                             unsigned short* __restrict__ w2p, unsigned short* __restrict__ w3p,
                                             unsigned short* __restrict__ wpp, unsigned short* __restrict__ wdp,
                                             const float* __restrict__ x, const float* __restrict__ W1,
                                             float* __restrict__ y1, float* __restrict__ st) {
  __shared__ float xs[48];
  __shared__ float w1s[864];
  __shared__ float sst[64];
  int t = threadIdx.x;
  if (blockIdx.x < 1080) {
    int i = blockIdx.x * 256 + t;
    if (i < 18432) packw_one(W2, w2p, 32, 64, 4, i);
    else if (i < 92160) packw_one(W3, w3p, 64, 128, 8, i - 18432);
    else if (i < 129024) packw_one(Wp, wpp, 128, 18, 2, i - 92160);
    else if (i < 276480) packwd_one(Wd, wdp, i - 129024);
    return;
  }
  int b = blockIdx.x - 1080;
  if (t < 48) xs[t] = x[b * 48 + t];
  for (int i = t; i < 864; i += 256) w1s[i] = W1[i];
  if (t < 64) sst[t] = 0.f;
  __syncthreads();
  for (int r = 0; r < 2; ++r) {
    int o = t + r * 256;
    int co = o >> 4, p = o & 15, h = p >> 2, w = p & 3;
    float acc = 0.f;
    for (int ci = 0; ci < 3; ++ci) {
#pragma unroll
      for (int kx = 0; kx < 3; ++kx) {
        int ih = h + kx - 1;
        if (ih < 0 || ih > 3) continue;
#pragma unroll
        for (int ky = 0; ky < 3; ++ky) {
          int iw = w + ky - 1;
          if (iw < 0 || iw > 3) continue;
          acc += w1s[co * 27 + ci * 9 + kx * 3 + ky] * xs[ci * 16 + ih * 4 + iw];
        }
      }
    }
    acc = fmaxf(acc, 0.f);
    y1[b * 512 + o] = acc;
    atomicAdd(&sst[co], acc);
    atomicAdd(&sst[32 + co], acc * acc);
  }
  __syncthreads();
  if (t < 64) atomicAdd(&st[(t < 32) ? t : (96 + t)], sst[t]);
}

// MFMA conv 3x3 pad1 over 4x4; 512 threads, 8 waves = (img, N-quarter); 2 images/block.
template <int CI, int CO>
__global__ __launch_bounds__(512, 8) void k_convm(const float* __restrict__ yin,
                                                  const unsigned short* __restrict__ wpk,
                                                  const float* __restrict__ stp,
                                                  const float* __restrict__ gp,
                                                  const float* __restrict__ bpar,
                                                  float* __restrict__ yout, float* __restrict__ stout) {
  constexpr int KST = CI / 32, NSTEP = 9 * KST, NT = CO / 16, TPW = NT / 4;
  constexpr int STR = 72;
  __shared__ __align__(16) unsigned short xnT[2][36 * STR];
  __shared__ float cst[2][CO * 16];
  __shared__ float scS[2 * CI];
  __shared__ float sst[2 * CO];
  int b0 = blockIdx.x * 2, t = threadIdx.x;
  uint4 z = {0u, 0u, 0u, 0u};
  for (int i = t; i < (2 * 36 * STR) / 8; i += 512) ((uint4*)xnT)[i] = z;
  if (t < CI) {
    float m = stp[t] / CNT;
    float v = stp[128 + t] / CNT - m * m;
    float s = gp[t] * rsqrtf(fmaxf(v, 0.f) + 1e-5f);
    scS[t] = s; scS[CI + t] = bpar[t] - m * s;
  }
  if (t < 2 * CO) sst[t] = 0.f;
  __syncthreads();
  for (int i = t; i < 2 * CI * 16; i += 512) {
    int img = i / (CI * 16), r = i - img * (CI * 16);
    int c = r >> 4, p = r & 15, h = p >> 2, w = p & 3;
    float v = yin[(b0 + img) * CI * 16 + r] * scS[c] + scS[CI + c];
    xnT[img][((h + 1) * 6 + (w + 1)) * STR + c] = f2bf(v);
  }
  __syncthreads();
  int wv = t >> 6, l = t & 63, px = l & 15, g = l >> 4;
  int h = px >> 2, w = px & 3;
  int img = wv >> 2, wq = wv & 3;
  f32x4 acc[TPW];
#pragma unroll
  for (int tw = 0; tw < TPW; ++tw) acc[tw] = f32x4{0.f, 0.f, 0.f, 0.f};
#pragma unroll
  for (int step = 0; step < NSTEP; ++step) {
    int tap = step / KST, ks = step - tap * KST;
    int kx = tap / 3, ky = tap % 3;
    bf16x8 a = *(const bf16x8*)&xnT[img][((h + kx) * 6 + (w + ky)) * STR + ks * 32 + g * 8];
#pragma unroll
    for (int tw = 0; tw < TPW; ++tw) {
      int nt = wq * TPW + tw;
      bf16x8 bb = *(const bf16x8*)&wpk[((step * NT + nt) * 64 + l) * 8];
      acc[tw] = __builtin_amdgcn_mfma_f32_16x16x32_bf16(a, bb, acc[tw], 0, 0, 0);
    }
  }
  int cc = l & 15;
#pragma unroll
  for (int tw = 0; tw < TPW; ++tw) {
    int co = (wq * TPW + tw) * 16 + cc;
#pragma unroll
    for (int r = 0; r < 4; ++r) cst[img][co * 16 + (g * 4 + r)] = acc[tw][r];
  }
  __syncthreads();
  // epilogue: 512 threads cover 2*CO*16 values
  {
    constexpr int EPT = CO / 16;          // 4 or 8 values per thread
    constexpr int TPC = 256 / CO;         // threads per channel (per image)
    int ime = t >> 8, tl = t & 255;
    int c = tl / TPC, e0 = (tl % TPC) * EPT;
    float s1 = 0.f, s2 = 0.f;
    float vr[EPT];
#pragma unroll
    for (int e = 0; e < EPT; ++e) {
      float v = fmaxf(cst[ime][c * 16 + e0 + e], 0.f);
      vr[e] = v; s1 += v; s2 += v * v;
    }
#pragma unroll
    for (int e = 0; e < EPT; e += 4)
      *(float4*)&yout[(b0 + ime) * CO * 16 + c * 16 + e0 + e] = make_float4(vr[e], vr[e + 1], vr[e + 2], vr[e + 3]);
    atomicAdd(&sst[c], s1);
    atomicAdd(&sst[CO + c], s2);
  }
  __syncthreads();
  if (t < 2 * CO) atomicAdd(&stout[(t < CO) ? t : (128 - CO + t)], sst[t]);
}

// deformable conv: 512 threads / 8 waves; MFMA offset conv + MFMA bilinear + 2-phase Wd GEMM
__global__ __launch_bounds__(512, 8) void k_deform(const float* __restrict__ y3,
                                                   const unsigned short* __restrict__ wppk,
                                                   const float* __restrict__ bp,
                                                   const unsigned short* __restrict__ wdp,
                                                   const float* __restrict__ stp,
                                                   const float* __restrict__ gp,
                                                   const float* __restrict__ bpar,
                                                   float* __restrict__ y4, float* __restrict__ stout) {
  __shared__ __align__(16) unsigned char smem[37568];
  unsigned short* xnb2 = (unsigned short*)smem;             // [0,6144) 128x24 ush (bilinear B)
  unsigned short* xnT  = (unsigned short*)(smem + 6144);    // [6144,15936) 36x136 padded tile
  unsigned short* sA   = (unsigned short*)(smem + 6144);    // overlay: S frags 9x16x32 (9216B)
  float* offs = (float*)(smem + 15936);                     // [15936,17088) 288 f32
  unsigned short* xoffA = (unsigned short*)(smem + 17088);  // [17088,35520) 18*512 ush (2-phase)
  float* cscr = (float*)(smem + 17088);                     // overlay: 8 waves x 256 f32 partials
  float* scS  = (float*)(smem + 35520);                     // 256 f32
  float* sst  = (float*)(smem + 36544);                     // 256 f32
  float* ystg = (float*)smem;                               // epilogue overlay [0,8192)
  int b = blockIdx.x, t = threadIdx.x;
  uint4 z = {0u, 0u, 0u, 0u};
  for (int i = t; i < 996; i += 512) ((uint4*)smem)[i] = z;  // zero xnb2 + xnT
  if (t < 128) {
    float m = stp[t] / CNT;
    float v = stp[128 + t] / CNT - m * m;
    float s = gp[t] * rsqrtf(fmaxf(v, 0.f) + 1e-5f);
    scS[t] = s; scS[128 + t] = bpar[t] - m * s;
  }
  if (t < 256) sst[t] = 0.f;
  __syncthreads();
  for (int i = t; i < 2048; i += 512) {
    int c = i >> 4, p = i & 15, h = p >> 2, w = p & 3;
    float v = y3[b * 2048 + i] * scS[c] + scS[128 + c];
    unsigned short bv = f2bf(v);
    xnb2[c * 24 + p] = bv;
    xnT[((h + 1) * 6 + (w + 1)) * 136 + c] = bv;
  }
  __syncthreads();
  int wv = t >> 6, l = t & 63, px = l & 15, g = l >> 4;
  int h = px >> 2, w = px & 3;
  // offset conv via MFMA: wave = (half = wv>>1, nt = wv&1); 9 K-steps each
  {
    int nt = wv & 1, half = wv >> 1;
    f32x4 oa = {0.f, 0.f, 0.f, 0.f};
#pragma unroll
    for (int si = 0; si < 9; ++si) {
      int s2 = half * 9 + si;
      int tap = s2 >> 2, ks = s2 & 3;
      int kx = tap / 3, ky = tap % 3;
      bf16x8 a = *(const bf16x8*)&xnT[((h + kx) * 6 + (w + ky)) * 136 + ks * 32 + g * 8];
      bf16x8 bb = *(const bf16x8*)&wppk[((s2 * 2 + nt) * 64 + l) * 8];
      oa = __builtin_amdgcn_mfma_f32_16x16x32_bf16(a, bb, oa, 0, 0, 0);
    }
#pragma unroll
    for (int r = 0; r < 4; ++r) cscr[wv * 256 + (g * 4 + r) * 16 + px] = oa[r];
  }
  __syncthreads();
  // reduce partials -> offs (t<288) ; zero sA (all threads; xnT dead)
  if (t < 288) {
    int o = t >> 4, pp = t & 15;
    int nt = o >> 4, cc = o & 15;
    float v = bp[o];
#pragma unroll
    for (int half = 0; half < 4; ++half) v += cscr[(half * 2 + nt) * 256 + pp * 16 + cc];
    offs[o * 16 + pp] = v;
  }
  for (int i = t; i < 576; i += 512) ((uint4*)sA)[i] = z;
  __syncthreads();
  // sampling -> scatter bilinear weights into S_n (bf16), chunk-swizzled by (px>>1)&3
  if (t < 144) {
    int p = t / 9, n = t % 9;
    int hh = p >> 2, ww = p & 3;
    float sx = offs[n * 16 + p] + (float)(hh + 1) + (float)(n / 3 - 1);
    float sy = offs[(9 + n) * 16 + p] + (float)(ww + 1) + (float)(n % 3 - 1);
    float fx = floorf(sx), fy = floorf(sy);
    float qlx = fminf(fmaxf(fx, 0.f), 5.f);
    float qly = fminf(fmaxf(fy, 0.f), 5.f);
    float qrx = fminf(fmaxf(fx + 1.f, 0.f), 5.f);
    float qry = fminf(fmaxf(fy + 1.f, 0.f), 5.f);
    float pxc = fminf(fmaxf(sx, 0.f), 5.f);
    float pyc = fminf(fmaxf(sy, 0.f), 5.f);
    float glt = (1.f + (qlx - pxc)) * (1.f + (qly - pyc));
    float grb = (1.f - (qrx - pxc)) * (1.f - (qry - pyc));
    float glb = (1.f + (qlx - pxc)) * (1.f - (qry - pyc));
    float grt = (1.f - (qrx - pxc)) * (1.f + (qly - pyc));
    int ilx = (int)qlx, ily = (int)qly, irx = (int)qrx, iry = (int)qry;
    int sw = (p >> 1) & 3;
    int rowb = (n * 16 + p) * 32;
    auto PUT = [&](int qx, int qy, float gv) {
      if (qx >= 1 && qx <= 4 && qy >= 1 && qy <= 4) {
        int pix = (qx - 1) * 4 + (qy - 1);
        sA[rowb + ((((pix >> 3) + sw) & 3) << 3) + (pix & 7)] = f2bf(gv);
      }
    };
    PUT(ilx, ily, glt);
    PUT(irx, iry, grb);
    PUT(ilx, iry, glb);
    PUT(irx, ily, grt);
  }
  __syncthreads();
  // 2 phases: MFMA bilinear builds xoffA for 18 K-steps; consume = 18 MFMA (wave = N-tile)
  f32x4 acc = {0.f, 0.f, 0.f, 0.f};
  int sw = (px >> 1) & 3;
  for (int ph = 0; ph < 2; ++ph) {
    for (int tau = wv; tau < 36; tau += 8) {
      int n = tau >> 2, ctl = tau & 3;
      int ct = 4 * ph + ctl;
      bf16x8 a = *(const bf16x8*)&sA[(n * 16 + px) * 32 + (((g + sw) & 3) << 3)];
      int ci = ct * 16 + px;
      bf16x8 bv = *(const bf16x8*)&xnb2[ci * 24 + g * 8];
      f32x4 d = __builtin_amdgcn_mfma_f32_16x16x32_bf16(a, bv, f32x4{0.f, 0.f, 0.f, 0.f}, 0, 0, 0);
      int k = ci * 9 + n;
      int tt_l = (k >> 5) - ph * 18, g2 = (k >> 3) & 3, j = k & 7;
      int base = (tt_l * 64 + g2 * 16) * 8 + j;
#pragma unroll
      for (int r = 0; r < 4; ++r) xoffA[base + (g * 4 + r) * 8] = f2bf(d[r]);
    }
    __syncthreads();
#pragma unroll
    for (int ti = 0; ti < 18; ++ti) {
      int tt = ph * 18 + ti;
      bf16x8 a = *(const bf16x8*)&xoffA[(ti * 64 + l) * 8];
      bf16x8 b0 = *(const bf16x8*)&wdp[((tt * 8 + wv) * 64 + l) * 8];
      acc = __builtin_amdgcn_mfma_f32_16x16x32_bf16(a, b0, acc, 0, 0, 0);
    }
    __syncthreads();
  }
  // stage C (xnb2/sA dead), then coalesced epilogue
  {
    int cc = l & 15, rg = l >> 4;
    int co = wv * 16 + cc;
#pragma unroll
    for (int r = 0; r < 4; ++r) ystg[co * 16 + rg * 4 + r] = acc[r];
  }
  __syncthreads();
  {
    int c = t >> 2, e0 = (t & 3) * 4;
    float s1 = 0.f, s2 = 0.f;
    float vr[4];
#pragma unroll
    for (int e = 0; e < 4; ++e) {
      float v = fmaxf(ystg[c * 16 + e0 + e], 0.f);
      vr[e] = v; s1 += v; s2 += v * v;
    }
    *(float4*)&y4[b * 2048 + c * 16 + e0] = make_float4(vr[0], vr[1], vr[2], vr[3]);
    atomicAdd(&sst[c], s1);
    atomicAdd(&sst[128 + c], s2);
  }
  __syncthreads();
  if (t < 256) atomicAdd(&stout[t], sst[t]);
}

// final: BN4-finalize folded + spatial mean + linear; 4 images per block
__global__ __launch_bounds__(256) void k_final(const float* __restrict__ y4,
                                               const float* __restrict__ stp,
                                               const float* __restrict__ gp,
                                               const float* __restrict__ bpar,
                                               const float* __restrict__ Wc, const float* __restrict__ bc,
                                               float* __restrict__ out) {
  __shared__ float vs[4][128];
  __shared__ float scS[256];
  int t = threadIdx.x, wv = t >> 6, l = t & 63;
  if (t < 128) {
    float m = stp[t] / CNT;
    float v = stp[128 + t] / CNT - m * m;
    float s = gp[t] * rsqrtf(fmaxf(v, 0.f) + 1e-5f);
    scS[t] = s; scS[128 + t] = bpar[t] - m * s;
  }
  __syncthreads();
  int img = blockIdx.x * 4 + wv;
  const float4* yp = (const float4*)(y4 + img * 2048);
  float4 a0 = yp[l * 8 + 0], a1 = yp[l * 8 + 1], a2 = yp[l * 8 + 2], a3 = yp[l * 8 + 3];
  float4 b0 = yp[l * 8 + 4], b1 = yp[l * 8 + 5], b2 = yp[l * 8 + 6], b3 = yp[l * 8 + 7];
  float s0 = (a0.x + a0.y + a0.z + a0.w) + (a1.x + a1.y + a1.z + a1.w) +
             (a2.x + a2.y + a2.z + a2.w) + (a3.x + a3.y + a3.z + a3.w);
  float s1 = (b0.x + b0.y + b0.z + b0.w) + (b1.x + b1.y + b1.z + b1.w) +
             (b2.x + b2.y + b2.z + b2.w) + (b3.x + b3.y + b3.z + b3.w);
  int c0 = l * 2, c1 = l * 2 + 1;
  vs[wv][c0] = scS[c0] * (s0 * 0.0625f) + scS[128 + c0];
  vs[wv][c1] = scS[c1] * (s1 * 0.0625f) + scS[128 + c1];
  __syncthreads();
  if (l < 40) {
    int o = l >> 2, q = l & 3;
    float p = 0.f;
    const float* wr = Wc + o * 128 + q * 32;
    const float* vr = &vs[wv][q * 32];
#pragma unroll
    for (int c = 0; c < 32; ++c) p += wr[c] * vr[c];
    p += __shfl_xor(p, 1);
    p += __shfl_xor(p, 2);
    if (q == 0) out[img * 10 + o] = p + bc[o];
  }
}

extern "C" void kernel_launch(void* const* d_in, const int* in_sizes, int n_in,
                              void* d_out, int out_size, void* d_ws, size_t ws_size,
                              hipStream_t stream) {
  const float* x  = (const float*)d_in[0];
  const float* W1 = (const float*)d_in[1];
  const float* g1 = (const float*)d_in[2];
  const float* b1 = (const float*)d_in[3];
  const float* W2 = (const float*)d_in[4];
  const float* g2 = (const float*)d_in[5];
  const float* b2 = (const float*)d_in[6];
  const float* W3 = (const float*)d_in[7];
  const float* g3 = (const float*)d_in[8];
  const float* b3 = (const float*)d_in[9];
  const float* Wp = (const float*)d_in[10];
  const float* bp = (const float*)d_in[11];
  const float* Wd = (const float*)d_in[12];
  const float* g4 = (const float*)d_in[13];
  const float* b4 = (const float*)d_in[14];
  const float* Wc = (const float*)d_in[15];
  const float* bc = (const float*)d_in[16];
  float* ws = (float*)d_ws;
  float* out = (float*)d_out;

  hipMemsetAsync(ws + OFF_ST, 0, 1024 * sizeof(float), stream);
  k_pre<<<3128, 256, 0, stream>>>(W2, W3, Wp, Wd,
                                  (unsigned short*)(ws + OFF_W2P), (unsigned short*)(ws + OFF_W3P),
                                  (unsigned short*)(ws + OFF_WPP), (unsigned short*)(ws + OFF_WDP),
                                  x, W1, ws + OFF_Y1, ws + OFF_ST);
  k_convm<32, 64><<<NB / 2, 512, 0, stream>>>(ws + OFF_Y1, (const unsigned short*)(ws + OFF_W2P),
                                              ws + OFF_ST, g1, b1, ws + OFF_Y2, ws + OFF_ST + 256);
  k_convm<64, 128><<<NB / 2, 512, 0, stream>>>(ws + OFF_Y2, (const unsigned short*)(ws + OFF_W3P),
                                               ws + OFF_ST + 256, g2, b2, ws + OFF_Y3, ws + OFF_ST + 512);
  k_deform<<<NB, 512, 0, stream>>>(ws + OFF_Y3, (const unsigned short*)(ws + OFF_WPP), bp,
                                   (const unsigned short*)(ws + OFF_WDP),
                                   ws + OFF_ST + 512, g3, b3, ws + OFF_Y4, ws + OFF_ST + 768);
  k_final<<<512, 256, 0, stream>>>(ws + OFF_Y4, ws + OFF_ST + 768, g4, b4, Wc, bc, out);
}

// Round 8
// 187.442 us; speedup vs baseline: 1.0437x; 1.0437x over previous
//
#include <hip/hip_runtime.h>

#define NB 2048
#define CNT 32768.0f   // per-channel count = B*H*W = 2048*16

// workspace float offsets
#define OFF_Y1   0          // 2048*32*16
#define OFF_Y2   1048576    // 2048*64*16
#define OFF_Y3   3145728    // 2048*128*16
#define OFF_Y4   7340032    // 2048*128*16
#define OFF_ST   11534336   // 4 layers x 256
#define OFF_W2P  11536384   // conv2 pack: 18432 ushort
#define OFF_W3P  11545600   // conv3 pack: 73728 ushort
#define OFF_WPP  11582464   // offset-conv pack: 36864 ushort
#define OFF_WDP  11600896   // Wd pack: 147456 ushort

typedef __attribute__((ext_vector_type(8))) short bf16x8;
typedef __attribute__((ext_vector_type(4))) float f32x4;

__device__ __forceinline__ unsigned short f2bf(float f) {
  union { float f; unsigned int u; } v; v.f = f;
  unsigned int r = v.u + 0x7FFFu + ((v.u >> 16) & 1u);
  return (unsigned short)(r >> 16);
}

// pack conv weight [CO][CI][3][3] -> bf16 B-fragments, tap-major K (step = tap*KST+ks)
__device__ __forceinline__ void packw_one(const float* __restrict__ w, unsigned short* __restrict__ wpk,
                                          int CI, int CO, int NT, int i) {
  int KST = CI >> 5;
  int j = i & 7, l = (i >> 3) & 63, sn = i >> 9;
  int nt = sn % NT, step = sn / NT;
  int tap = step / KST, ks = step - tap * KST;
  int ci = ks * 32 + (l >> 4) * 8 + j, co = nt * 16 + (l & 15);
  wpk[i] = (co < CO) ? f2bf(w[(co * CI + ci) * 9 + tap]) : (unsigned short)0;
}

// pack Wd: K order k = ci*9 + tap (verified)
__device__ __forceinline__ void packwd_one(const float* __restrict__ Wd, unsigned short* __restrict__ wdp, int i) {
  int co = i / 1152, k = i % 1152;
  int t = k >> 5, kk = k & 31, g = kk >> 3, j = kk & 7;
  int nt = co >> 4, cc = co & 15, l = g * 16 + cc;
  wdp[((t * 8 + nt) * 64 + l) * 8 + j] = f2bf(Wd[i]);
}

// merged: blocks [0,1080) pack weights; blocks [1080,3128) run conv1 (3->32, fp32)
__global__ __launch_bounds__(256) void k_pre(const float* __restrict__ W2, const float* __restrict__ W3,
                                             const float* __restrict__ Wp, const float* __restrict__ Wd,
                                             unsigned short* __restrict__ w2p, unsigned short* __restrict__ w3p,
                                             unsigned short* __restrict__ wpp, unsigned short* __restrict__ wdp,
                                             const float* __restrict__ x, const float* __restrict__ W1,
                                             float* __restrict__ y1, float* __restrict__ st) {
  __shared__ float xs[48];
  __shared__ float w1s[864];
  __shared__ float sst[64];
  int t = threadIdx.x;
  if (blockIdx.x < 1080) {
    int i = blockIdx.x * 256 + t;
    if (i < 18432) packw_one(W2, w2p, 32, 64, 4, i);
    else if (i < 92160) packw_one(W3, w3p, 64, 128, 8, i - 18432);
    else if (i < 129024) packw_one(Wp, wpp, 128, 18, 2, i - 92160);
    else if (i < 276480) packwd_one(Wd, wdp, i - 129024);
    return;
  }
  int b = blockIdx.x - 1080;
  if (t < 48) xs[t] = x[b * 48 + t];
  for (int i = t; i < 864; i += 256) w1s[i] = W1[i];
  if (t < 64) sst[t] = 0.f;
  __syncthreads();
  for (int r = 0; r < 2; ++r) {
    int o = t + r * 256;
    int co = o >> 4, p = o & 15, h = p >> 2, w = p & 3;
    float acc = 0.f;
    for (int ci = 0; ci < 3; ++ci) {
#pragma unroll
      for (int kx = 0; kx < 3; ++kx) {
        int ih = h + kx - 1;
        if (ih < 0 || ih > 3) continue;
#pragma unroll
        for (int ky = 0; ky < 3; ++ky) {
          int iw = w + ky - 1;
          if (iw < 0 || iw > 3) continue;
          acc += w1s[co * 27 + ci * 9 + kx * 3 + ky] * xs[ci * 16 + ih * 4 + iw];
        }
      }
    }
    acc = fmaxf(acc, 0.f);
    y1[b * 512 + o] = acc;
    atomicAdd(&sst[co], acc);
    atomicAdd(&sst[32 + co], acc * acc);
  }
  __syncthreads();
  if (t < 64) atomicAdd(&st[(t < 32) ? t : (96 + t)], sst[t]);
}

// MFMA conv 3x3 pad1 over 4x4; 512 threads, 8 waves = (img, N-quarter); 2 images/block.
// launch_bounds(512,4): VGPR cap 128 so B-fragment loads can pipeline (R6 had 32 -> serialized).
template <int CI, int CO>
__global__ __launch_bounds__(512, 4) void k_convm(const float* __restrict__ yin,
                                                  const unsigned short* __restrict__ wpk,
                                                  const float* __restrict__ stp,
                                                  const float* __restrict__ gp,
                                                  const float* __restrict__ bpar,
                                                  float* __restrict__ yout, float* __restrict__ stout) {
  constexpr int KST = CI / 32, NSTEP = 9 * KST, NT = CO / 16, TPW = NT / 4;
  constexpr int STR = 72;
  __shared__ __align__(16) unsigned short xnT[2][36 * STR];
  __shared__ float cst[2][CO * 16];
  __shared__ float scS[2 * CI];
  __shared__ float sst[2 * CO];
  int b0 = blockIdx.x * 2, t = threadIdx.x;
  uint4 z = {0u, 0u, 0u, 0u};
  for (int i = t; i < (2 * 36 * STR) / 8; i += 512) ((uint4*)xnT)[i] = z;
  if (t < CI) {
    float m = stp[t] / CNT;
    float v = stp[128 + t] / CNT - m * m;
    float s = gp[t] * rsqrtf(fmaxf(v, 0.f) + 1e-5f);
    scS[t] = s; scS[CI + t] = bpar[t] - m * s;
  }
  if (t < 2 * CO) sst[t] = 0.f;
  __syncthreads();
  for (int i = t; i < 2 * CI * 16; i += 512) {
    int img = i / (CI * 16), r = i - img * (CI * 16);
    int c = r >> 4, p = r & 15, h = p >> 2, w = p & 3;
    float v = yin[(b0 + img) * CI * 16 + r] * scS[c] + scS[CI + c];
    xnT[img][((h + 1) * 6 + (w + 1)) * STR + c] = f2bf(v);
  }
  __syncthreads();
  int wv = t >> 6, l = t & 63, px = l & 15, g = l >> 4;
  int h = px >> 2, w = px & 3;
  int img = wv >> 2, wq = wv & 3;
  f32x4 acc[TPW];
#pragma unroll
  for (int tw = 0; tw < TPW; ++tw) acc[tw] = f32x4{0.f, 0.f, 0.f, 0.f};
#pragma unroll
  for (int step = 0; step < NSTEP; ++step) {
    int tap = step / KST, ks = step - tap * KST;
    int kx = tap / 3, ky = tap % 3;
    bf16x8 a = *(const bf16x8*)&xnT[img][((h + kx) * 6 + (w + ky)) * STR + ks * 32 + g * 8];
#pragma unroll
    for (int tw = 0; tw < TPW; ++tw) {
      int nt = wq * TPW + tw;
      bf16x8 bb = *(const bf16x8*)&wpk[((step * NT + nt) * 64 + l) * 8];
      acc[tw] = __builtin_amdgcn_mfma_f32_16x16x32_bf16(a, bb, acc[tw], 0, 0, 0);
    }
  }
  int cc = l & 15;
#pragma unroll
  for (int tw = 0; tw < TPW; ++tw) {
    int co = (wq * TPW + tw) * 16 + cc;
#pragma unroll
    for (int r = 0; r < 4; ++r) cst[img][co * 16 + (g * 4 + r)] = acc[tw][r];
  }
  __syncthreads();
  // epilogue: 512 threads cover 2*CO*16 values
  {
    constexpr int EPT = CO / 16;          // 4 or 8 values per thread
    constexpr int TPC = 256 / CO;         // threads per channel (per image)
    int ime = t >> 8, tl = t & 255;
    int c = tl / TPC, e0 = (tl % TPC) * EPT;
    float s1 = 0.f, s2 = 0.f;
    float vr[EPT];
#pragma unroll
    for (int e = 0; e < EPT; ++e) {
      float v = fmaxf(cst[ime][c * 16 + e0 + e], 0.f);
      vr[e] = v; s1 += v; s2 += v * v;
    }
#pragma unroll
    for (int e = 0; e < EPT; e += 4)
      *(float4*)&yout[(b0 + ime) * CO * 16 + c * 16 + e0 + e] = make_float4(vr[e], vr[e + 1], vr[e + 2], vr[e + 3]);
    atomicAdd(&sst[c], s1);
    atomicAdd(&sst[CO + c], s2);
  }
  __syncthreads();
  if (t < 2 * CO) atomicAdd(&stout[(t < CO) ? t : (128 - CO + t)], sst[t]);
}

// deformable conv: 512 threads / 8 waves; MFMA offset conv + MFMA bilinear + 2-phase Wd GEMM.
// launch_bounds(512,4): VGPR cap 128 -> bb[18] phase prefetch fits; 2 blocks/CU retained.
__global__ __launch_bounds__(512, 4) void k_deform(const float* __restrict__ y3,
                                                   const unsigned short* __restrict__ wppk,
                                                   const float* __restrict__ bp,
                                                   const unsigned short* __restrict__ wdp,
                                                   const float* __restrict__ stp,
                                                   const float* __restrict__ gp,
                                                   const float* __restrict__ bpar,
                                                   float* __restrict__ y4, float* __restrict__ stout) {
  __shared__ __align__(16) unsigned char smem[37568];
  unsigned short* xnb2 = (unsigned short*)smem;             // [0,6144) 128x24 ush (bilinear B)
  unsigned short* xnT  = (unsigned short*)(smem + 6144);    // [6144,15936) 36x136 padded tile
  unsigned short* sA   = (unsigned short*)(smem + 6144);    // overlay: S frags 9x16x32 (9216B)
  float* offs = (float*)(smem + 15936);                     // [15936,17088) 288 f32
  unsigned short* xoffA = (unsigned short*)(smem + 17088);  // [17088,35520) 18*512 ush (2-phase)
  float* cscr = (float*)(smem + 17088);                     // overlay: 8 waves x 256 f32 partials
  float* scS  = (float*)(smem + 35520);                     // 256 f32
  float* sst  = (float*)(smem + 36544);                     // 256 f32
  float* ystg = (float*)smem;                               // epilogue overlay [0,8192)
  int b = blockIdx.x, t = threadIdx.x;
  uint4 z = {0u, 0u, 0u, 0u};
  for (int i = t; i < 996; i += 512) ((uint4*)smem)[i] = z;  // zero xnb2 + xnT
  if (t < 128) {
    float m = stp[t] / CNT;
    float v = stp[128 + t] / CNT - m * m;
    float s = gp[t] * rsqrtf(fmaxf(v, 0.f) + 1e-5f);
    scS[t] = s; scS[128 + t] = bpar[t] - m * s;
  }
  if (t < 256) sst[t] = 0.f;
  __syncthreads();
  for (int i = t; i < 2048; i += 512) {
    int c = i >> 4, p = i & 15, h = p >> 2, w = p & 3;
    float v = y3[b * 2048 + i] * scS[c] + scS[128 + c];
    unsigned short bv = f2bf(v);
    xnb2[c * 24 + p] = bv;
    xnT[((h + 1) * 6 + (w + 1)) * 136 + c] = bv;
  }
  __syncthreads();
  int wv = t >> 6, l = t & 63, px = l & 15, g = l >> 4;
  int h = px >> 2, w = px & 3;
  // offset conv via MFMA: wave = (half = wv>>1, nt = wv&1); 9 K-steps each
  {
    int nt = wv & 1, half = wv >> 1;
    f32x4 oa = {0.f, 0.f, 0.f, 0.f};
#pragma unroll
    for (int si = 0; si < 9; ++si) {
      int s2 = half * 9 + si;
      int tap = s2 >> 2, ks = s2 & 3;
      int kx = tap / 3, ky = tap % 3;
      bf16x8 a = *(const bf16x8*)&xnT[((h + kx) * 6 + (w + ky)) * 136 + ks * 32 + g * 8];
      bf16x8 bb = *(const bf16x8*)&wppk[((s2 * 2 + nt) * 64 + l) * 8];
      oa = __builtin_amdgcn_mfma_f32_16x16x32_bf16(a, bb, oa, 0, 0, 0);
    }
#pragma unroll
    for (int r = 0; r < 4; ++r) cscr[wv * 256 + (g * 4 + r) * 16 + px] = oa[r];
  }
  __syncthreads();
  // reduce partials -> offs (t<288) ; zero sA (all threads; xnT dead)
  if (t < 288) {
    int o = t >> 4, pp = t & 15;
    int nt = o >> 4, cc2 = o & 15;
    float v = bp[o];
#pragma unroll
    for (int half = 0; half < 4; ++half) v += cscr[(half * 2 + nt) * 256 + pp * 16 + cc2];
    offs[o * 16 + pp] = v;
  }
  for (int i = t; i < 576; i += 512) ((uint4*)sA)[i] = z;
  __syncthreads();
  // sampling -> scatter bilinear weights into S_n (bf16), chunk-swizzled by (px>>1)&3
  if (t < 144) {
    int p = t / 9, n = t % 9;
    int hh = p >> 2, ww = p & 3;
    float sx = offs[n * 16 + p] + (float)(hh + 1) + (float)(n / 3 - 1);
    float sy = offs[(9 + n) * 16 + p] + (float)(ww + 1) + (float)(n % 3 - 1);
    float fx = floorf(sx), fy = floorf(sy);
    float qlx = fminf(fmaxf(fx, 0.f), 5.f);
    float qly = fminf(fmaxf(fy, 0.f), 5.f);
    float qrx = fminf(fmaxf(fx + 1.f, 0.f), 5.f);
    float qry = fminf(fmaxf(fy + 1.f, 0.f), 5.f);
    float pxc = fminf(fmaxf(sx, 0.f), 5.f);
    float pyc = fminf(fmaxf(sy, 0.f), 5.f);
    float glt = (1.f + (qlx - pxc)) * (1.f + (qly - pyc));
    float grb = (1.f - (qrx - pxc)) * (1.f - (qry - pyc));
    float glb = (1.f + (qlx - pxc)) * (1.f - (qry - pyc));
    float grt = (1.f - (qrx - pxc)) * (1.f + (qly - pyc));
    int ilx = (int)qlx, ily = (int)qly, irx = (int)qrx, iry = (int)qry;
    int swp = (p >> 1) & 3;
    int rowb = (n * 16 + p) * 32;
    auto PUT = [&](int qx, int qy, float gv) {
      if (qx >= 1 && qx <= 4 && qy >= 1 && qy <= 4) {
        int pix = (qx - 1) * 4 + (qy - 1);
        sA[rowb + ((((pix >> 3) + swp) & 3) << 3) + (pix & 7)] = f2bf(gv);
      }
    };
    PUT(ilx, ily, glt);
    PUT(irx, iry, grb);
    PUT(ilx, iry, glb);
    PUT(irx, ily, grt);
  }
  __syncthreads();
  // 2 phases: prefetch 18 B-frags (global, L2) BEFORE bilinear build so latency hides,
  // then bilinear MFMA builds xoffA, then 18 back-to-back MFMAs consume.
  f32x4 acc = {0.f, 0.f, 0.f, 0.f};
  int sw = (px >> 1) & 3;
  for (int ph = 0; ph < 2; ++ph) {
    bf16x8 bb[18];
#pragma unroll
    for (int ti = 0; ti < 18; ++ti)
      bb[ti] = *(const bf16x8*)&wdp[(((ph * 18 + ti) * 8 + wv) * 64 + l) * 8];
    for (int tau = wv; tau < 36; tau += 8) {
      int n = tau >> 2, ctl = tau & 3;
      int ct = 4 * ph + ctl;
      bf16x8 a = *(const bf16x8*)&sA[(n * 16 + px) * 32 + (((g + sw) & 3) << 3)];
      int ci = ct * 16 + px;
      bf16x8 bv = *(const bf16x8*)&xnb2[ci * 24 + g * 8];
      f32x4 d = __builtin_amdgcn_mfma_f32_16x16x32_bf16(a, bv, f32x4{0.f, 0.f, 0.f, 0.f}, 0, 0, 0);
      int k = ci * 9 + n;
      int tt_l = (k >> 5) - ph * 18, g2 = (k >> 3) & 3, j = k & 7;
      int base = (tt_l * 64 + g2 * 16) * 8 + j;
#pragma unroll
      for (int r = 0; r < 4; ++r) xoffA[base + (g * 4 + r) * 8] = f2bf(d[r]);
    }
    __syncthreads();
#pragma unroll
    for (int ti = 0; ti < 18; ++ti) {
      bf16x8 a = *(const bf16x8*)&xoffA[(ti * 64 + l) * 8];
      acc = __builtin_amdgcn_mfma_f32_16x16x32_bf16(a, bb[ti], acc, 0, 0, 0);
    }
    __syncthreads();
  }
  // stage C (xnb2/sA dead), then coalesced epilogue
  {
    int cc = l & 15, rg = l >> 4;
    int co = wv * 16 + cc;
#pragma unroll
    for (int r = 0; r < 4; ++r) ystg[co * 16 + rg * 4 + r] = acc[r];
  }
  __syncthreads();
  {
    int c = t >> 2, e0 = (t & 3) * 4;
    float s1 = 0.f, s2 = 0.f;
    float vr[4];
#pragma unroll
    for (int e = 0; e < 4; ++e) {
      float v = fmaxf(ystg[c * 16 + e0 + e], 0.f);
      vr[e] = v; s1 += v; s2 += v * v;
    }
    *(float4*)&y4[b * 2048 + c * 16 + e0] = make_float4(vr[0], vr[1], vr[2], vr[3]);
    atomicAdd(&sst[c], s1);
    atomicAdd(&sst[128 + c], s2);
  }
  __syncthreads();
  if (t < 256) atomicAdd(&stout[t], sst[t]);
}

// final: BN4-finalize folded + spatial mean + linear; 4 images per block
__global__ __launch_bounds__(256) void k_final(const float* __restrict__ y4,
                                               const float* __restrict__ stp,
                                               const float* __restrict__ gp,
                                               const float* __restrict__ bpar,
                                               const float* __restrict__ Wc, const float* __restrict__ bc,
                                               float* __restrict__ out) {
  __shared__ float vs[4][128];
  __shared__ float scS[256];
  int t = threadIdx.x, wv = t >> 6, l = t & 63;
  if (t < 128) {
    float m = stp[t] / CNT;
    float v = stp[128 + t] / CNT - m * m;
    float s = gp[t] * rsqrtf(fmaxf(v, 0.f) + 1e-5f);
    scS[t] = s; scS[128 + t] = bpar[t] - m * s;
  }
  __syncthreads();
  int img = blockIdx.x * 4 + wv;
  const float4* yp = (const float4*)(y4 + img * 2048);
  float4 a0 = yp[l * 8 + 0], a1 = yp[l * 8 + 1], a2 = yp[l * 8 + 2], a3 = yp[l * 8 + 3];
  float4 b0 = yp[l * 8 + 4], b1 = yp[l * 8 + 5], b2 = yp[l * 8 + 6], b3 = yp[l * 8 + 7];
  float s0 = (a0.x + a0.y + a0.z + a0.w) + (a1.x + a1.y + a1.z + a1.w) +
             (a2.x + a2.y + a2.z + a2.w) + (a3.x + a3.y + a3.z + a3.w);
  float s1 = (b0.x + b0.y + b0.z + b0.w) + (b1.x + b1.y + b1.z + b1.w) +
             (b2.x + b2.y + b2.z + b2.w) + (b3.x + b3.y + b3.z + b3.w);
  int c0 = l * 2, c1 = l * 2 + 1;
  vs[wv][c0] = scS[c0] * (s0 * 0.0625f) + scS[128 + c0];
  vs[wv][c1] = scS[c1] * (s1 * 0.0625f) + scS[128 + c1];
  __syncthreads();
  if (l < 40) {
    int o = l >> 2, q = l & 3;
    float p = 0.f;
    const float* wr = Wc + o * 128 + q * 32;
    const float* vr = &vs[wv][q * 32];
#pragma unroll
    for (int c = 0; c < 32; ++c) p += wr[c] * vr[c];
    p += __shfl_xor(p, 1);
    p += __shfl_xor(p, 2);
    if (q == 0) out[img * 10 + o] = p + bc[o];
  }
}

extern "C" void kernel_launch(void* const* d_in, const int* in_sizes, int n_in,
                              void* d_out, int out_size, void* d_ws, size_t ws_size,
                              hipStream_t stream) {
  const float* x  = (const float*)d_in[0];
  const float* W1 = (const float*)d_in[1];
  const float* g1 = (const float*)d_in[2];
  const float* b1 = (const float*)d_in[3];
  const float* W2 = (const float*)d_in[4];
  const float* g2 = (const float*)d_in[5];
  const float* b2 = (const float*)d_in[6];
  const float* W3 = (const float*)d_in[7];
  const float* g3 = (const float*)d_in[8];
  const float* b3 = (const float*)d_in[9];
  const float* Wp = (const float*)d_in[10];
  const float* bp = (const float*)d_in[11];
  const float* Wd = (const float*)d_in[12];
  const float* g4 = (const float*)d_in[13];
  const float* b4 = (const float*)d_in[14];
  const float* Wc = (const float*)d_in[15];
  const float* bc = (const float*)d_in[16];
  float* ws = (float*)d_ws;
  float* out = (float*)d_out;

  hipMemsetAsync(ws + OFF_ST, 0, 1024 * sizeof(float), stream);
  k_pre<<<3128, 256, 0, stream>>>(W2, W3, Wp, Wd,
                                  (unsigned short*)(ws + OFF_W2P), (unsigned short*)(ws + OFF_W3P),
                                  (unsigned short*)(ws + OFF_WPP), (unsigned short*)(ws + OFF_WDP),
                                  x, W1, ws + OFF_Y1, ws + OFF_ST);
  k_convm<32, 64><<<NB / 2, 512, 0, stream>>>(ws + OFF_Y1, (const unsigned short*)(ws + OFF_W2P),
                                              ws + OFF_ST, g1, b1, ws + OFF_Y2, ws + OFF_ST + 256);
  k_convm<64, 128><<<NB / 2, 512, 0, stream>>>(ws + OFF_Y2, (const unsigned short*)(ws + OFF_W3P),
                                               ws + OFF_ST + 256, g2, b2, ws + OFF_Y3, ws + OFF_ST + 512);
  k_deform<<<NB, 512, 0, stream>>>(ws + OFF_Y3, (const unsigned short*)(ws + OFF_WPP), bp,
                                   (const unsigned short*)(ws + OFF_WDP),
                                   ws + OFF_ST + 512, g3, b3, ws + OFF_Y4, ws + OFF_ST + 768);
  k_final<<<512, 256, 0, stream>>>(ws + OFF_Y4, ws + OFF_ST + 768, g4, b4, Wc, bc, out);
}

// Round 9
// 168.354 us; speedup vs baseline: 1.1620x; 1.1134x over previous
//
#include <hip/hip_runtime.h>

#define NB 2048
#define CNT 32768.0f   // per-channel count = B*H*W = 2048*16

// workspace float offsets
#define OFF_Y1   0          // 2048*32*16
#define OFF_Y2   1048576    // 2048*64*16
#define OFF_Y3   3145728    // 2048*128*16
#define OFF_Y4   7340032    // 2048*128*16
#define OFF_ST   11534336   // 4 layers x 256
#define OFF_W2P  11536384   // conv2 pack: 18432 ushort
#define OFF_W3P  11545600   // conv3 pack: 73728 ushort
#define OFF_WPP  11582464   // offset-conv pack: 36864 ushort
#define OFF_WDP  11600896   // Wd pack: 147456 ushort

typedef __attribute__((ext_vector_type(8))) short bf16x8;
typedef __attribute__((ext_vector_type(4))) float f32x4;

__device__ __forceinline__ unsigned short f2bf(float f) {
  union { float f; unsigned int u; } v; v.f = f;
  unsigned int r = v.u + 0x7FFFu + ((v.u >> 16) & 1u);
  return (unsigned short)(r >> 16);
}

// pack conv weight [CO][CI][3][3] -> bf16 B-fragments, tap-major K (step = tap*KST+ks)
__device__ __forceinline__ void packw_one(const float* __restrict__ w, unsigned short* __restrict__ wpk,
                                          int CI, int CO, int NT, int i) {
  int KST = CI >> 5;
  int j = i & 7, l = (i >> 3) & 63, sn = i >> 9;
  int nt = sn % NT, step = sn / NT;
  int tap = step / KST, ks = step - tap * KST;
  int ci = ks * 32 + (l >> 4) * 8 + j, co = nt * 16 + (l & 15);
  wpk[i] = (co < CO) ? f2bf(w[(co * CI + ci) * 9 + tap]) : (unsigned short)0;
}

// pack Wd with NEW K-order k = n*128 + ci  (n = tap index)
__device__ __forceinline__ void packwd_one(const float* __restrict__ Wd, unsigned short* __restrict__ wdp, int i) {
  int co = i / 1152, k = i % 1152;
  int n = k >> 7, ci = k & 127;
  int tt = k >> 5, kk = k & 31, g = kk >> 3, j = kk & 7;
  int nt = co >> 4, cc = co & 15, l = g * 16 + cc;
  wdp[((tt * 8 + nt) * 64 + l) * 8 + j] = f2bf(Wd[co * 1152 + ci * 9 + n]);
}

// merged: blocks [0,270) pack weights (4 elems/thread); blocks [270,782) conv1, 4 images each
__global__ __launch_bounds__(256) void k_pre(const float* __restrict__ W2, const float* __restrict__ W3,
                                             const float* __restrict__ Wp, const float* __restrict__ Wd,
                                             unsigned short* __restrict__ w2p, unsigned short* __restrict__ w3p,
                                             unsigned short* __restrict__ wpp, unsigned short* __restrict__ wdp,
                                             const float* __restrict__ x, const float* __restrict__ W1,
                                             float* __restrict__ y1, float* __restrict__ st) {
  __shared__ float xs[192];
  __shared__ float w1s[864];
  __shared__ float sst[64];
  int t = threadIdx.x;
  if (blockIdx.x < 270) {
#pragma unroll
    for (int ii = 0; ii < 4; ++ii) {
      int i = blockIdx.x * 1024 + ii * 256 + t;
      if (i < 18432) packw_one(W2, w2p, 32, 64, 4, i);
      else if (i < 92160) packw_one(W3, w3p, 64, 128, 8, i - 18432);
      else if (i < 129024) packw_one(Wp, wpp, 128, 18, 2, i - 92160);
      else if (i < 276480) packwd_one(Wd, wdp, i - 129024);
    }
    return;
  }
  int b0 = (blockIdx.x - 270) * 4;
  if (t < 192) xs[t] = x[b0 * 48 + t];
  for (int i = t; i < 864; i += 256) w1s[i] = W1[i];
  if (t < 64) sst[t] = 0.f;
  __syncthreads();
  for (int r = 0; r < 2; ++r) {
    int o = t + r * 256;
    int co = o >> 4, p = o & 15, h = p >> 2, w = p & 3;
    float s1 = 0.f, s2 = 0.f;
#pragma unroll
    for (int img = 0; img < 4; ++img) {
      float acc = 0.f;
      for (int ci = 0; ci < 3; ++ci) {
#pragma unroll
        for (int kx = 0; kx < 3; ++kx) {
          int ih = h + kx - 1;
          if (ih < 0 || ih > 3) continue;
#pragma unroll
          for (int ky = 0; ky < 3; ++ky) {
            int iw = w + ky - 1;
            if (iw < 0 || iw > 3) continue;
            acc += w1s[co * 27 + ci * 9 + kx * 3 + ky] * xs[img * 48 + ci * 16 + ih * 4 + iw];
          }
        }
      }
      acc = fmaxf(acc, 0.f);
      y1[(b0 + img) * 512 + o] = acc;
      s1 += acc; s2 += acc * acc;
    }
    atomicAdd(&sst[co], s1);
    atomicAdd(&sst[32 + co], s2);
  }
  __syncthreads();
  if (t < 64) atomicAdd(&st[(t < 32) ? t : (96 + t)], sst[t]);
}

// MFMA conv 3x3 pad1 over 4x4; 512 threads, 8 waves = (img, N-quarter); 2 images/block.
template <int CI, int CO>
__global__ __launch_bounds__(512, 4) void k_convm(const float* __restrict__ yin,
                                                  const unsigned short* __restrict__ wpk,
                                                  const float* __restrict__ stp,
                                                  const float* __restrict__ gp,
                                                  const float* __restrict__ bpar,
                                                  float* __restrict__ yout, float* __restrict__ stout) {
  constexpr int KST = CI / 32, NSTEP = 9 * KST, NT = CO / 16, TPW = NT / 4;
  constexpr int STR = 72;
  __shared__ __align__(16) unsigned short xnT[2][36 * STR];
  __shared__ float cst[2][CO * 16];
  __shared__ float scS[2 * CI];
  __shared__ float sst[2 * CO];
  int b0 = blockIdx.x * 2, t = threadIdx.x;
  uint4 z = {0u, 0u, 0u, 0u};
  for (int i = t; i < (2 * 36 * STR) / 8; i += 512) ((uint4*)xnT)[i] = z;
  if (t < CI) {
    float m = stp[t] / CNT;
    float v = stp[128 + t] / CNT - m * m;
    float s = gp[t] * rsqrtf(fmaxf(v, 0.f) + 1e-5f);
    scS[t] = s; scS[CI + t] = bpar[t] - m * s;
  }
  if (t < 2 * CO) sst[t] = 0.f;
  __syncthreads();
  for (int i = t; i < 2 * CI * 16; i += 512) {
    int img = i / (CI * 16), r = i - img * (CI * 16);
    int c = r >> 4, p = r & 15, h = p >> 2, w = p & 3;
    float v = yin[(b0 + img) * CI * 16 + r] * scS[c] + scS[CI + c];
    xnT[img][((h + 1) * 6 + (w + 1)) * STR + c] = f2bf(v);
  }
  __syncthreads();
  int wv = t >> 6, l = t & 63, px = l & 15, g = l >> 4;
  int h = px >> 2, w = px & 3;
  int img = wv >> 2, wq = wv & 3;
  f32x4 acc[TPW];
#pragma unroll
  for (int tw = 0; tw < TPW; ++tw) acc[tw] = f32x4{0.f, 0.f, 0.f, 0.f};
#pragma unroll
  for (int step = 0; step < NSTEP; ++step) {
    int tap = step / KST, ks = step - tap * KST;
    int kx = tap / 3, ky = tap % 3;
    bf16x8 a = *(const bf16x8*)&xnT[img][((h + kx) * 6 + (w + ky)) * STR + ks * 32 + g * 8];
#pragma unroll
    for (int tw = 0; tw < TPW; ++tw) {
      int nt = wq * TPW + tw;
      bf16x8 bb = *(const bf16x8*)&wpk[((step * NT + nt) * 64 + l) * 8];
      acc[tw] = __builtin_amdgcn_mfma_f32_16x16x32_bf16(a, bb, acc[tw], 0, 0, 0);
    }
  }
  int cc = l & 15;
#pragma unroll
  for (int tw = 0; tw < TPW; ++tw) {
    int co = (wq * TPW + tw) * 16 + cc;
#pragma unroll
    for (int r = 0; r < 4; ++r) cst[img][co * 16 + (g * 4 + r)] = acc[tw][r];
  }
  __syncthreads();
  {
    constexpr int EPT = CO / 16;
    constexpr int TPC = 256 / CO;
    int ime = t >> 8, tl = t & 255;
    int c = tl / TPC, e0 = (tl % TPC) * EPT;
    float s1 = 0.f, s2 = 0.f;
    float vr[EPT];
#pragma unroll
    for (int e = 0; e < EPT; ++e) {
      float v = fmaxf(cst[ime][c * 16 + e0 + e], 0.f);
      vr[e] = v; s1 += v; s2 += v * v;
    }
#pragma unroll
    for (int e = 0; e < EPT; e += 4)
      *(float4*)&yout[(b0 + ime) * CO * 16 + c * 16 + e0 + e] = make_float4(vr[e], vr[e + 1], vr[e + 2], vr[e + 3]);
    atomicAdd(&sst[c], s1);
    atomicAdd(&sst[CO + c], s2);
  }
  __syncthreads();
  if (t < 2 * CO) atomicAdd(&stout[(t < CO) ? t : (128 - CO + t)], sst[t]);
}

// deformable conv: swapped-operand bilinear build (contiguous b64 xoffA writes), K = n*128+ci.
__global__ __launch_bounds__(512, 4) void k_deform(const float* __restrict__ y3,
                                                   const unsigned short* __restrict__ wppk,
                                                   const float* __restrict__ bp,
                                                   const unsigned short* __restrict__ wdp,
                                                   const float* __restrict__ stp,
                                                   const float* __restrict__ gp,
                                                   const float* __restrict__ bpar,
                                                   float* __restrict__ y4, float* __restrict__ stout) {
  __shared__ __align__(16) unsigned char smem[39296];
  unsigned short* xnb2 = (unsigned short*)smem;             // [0,6144) 128x24 ush  [ci][pix] (pad 16-23 = 0)
  unsigned short* xnT  = (unsigned short*)(smem + 6144);    // [6144,15936) 36x136 (offset conv)
  unsigned short* sAT  = (unsigned short*)(smem + 6144);    // overlay: S^T frags 9x16x40 ush (11520B)
  unsigned short* xoffA = (unsigned short*)(smem + 17664);  // [17664,36096) 18*512 ush per phase
  float* cscr = (float*)(smem + 17664);                     // overlay: 8x256 f32 offset-conv partials
  float* offs = (float*)(smem + 36096);                     // 288 f32
  float* scS  = (float*)(smem + 37248);                     // 256 f32
  float* sst  = (float*)(smem + 38272);                     // 256 f32
  float* ystg = (float*)smem;                               // epilogue overlay [0,8192)
  int b = blockIdx.x, t = threadIdx.x;
  uint4 z = {0u, 0u, 0u, 0u};
  for (int i = t; i < 996; i += 512) ((uint4*)smem)[i] = z;  // zero xnb2 + xnT
  if (t < 128) {
    float m = stp[t] / CNT;
    float v = stp[128 + t] / CNT - m * m;
    float s = gp[t] * rsqrtf(fmaxf(v, 0.f) + 1e-5f);
    scS[t] = s; scS[128 + t] = bpar[t] - m * s;
  }
  if (t < 256) sst[t] = 0.f;
  __syncthreads();
  for (int i = t; i < 2048; i += 512) {
    int c = i >> 4, p = i & 15, h = p >> 2, w = p & 3;
    float v = y3[b * 2048 + i] * scS[c] + scS[128 + c];
    unsigned short bv = f2bf(v);
    xnb2[c * 24 + p] = bv;
    xnT[((h + 1) * 6 + (w + 1)) * 136 + c] = bv;
  }
  __syncthreads();
  int wv = t >> 6, l = t & 63, px = l & 15, g = l >> 4, cc = l & 15;
  int h = px >> 2, w = px & 3;
  // offset conv via MFMA: wave = (half = wv>>1, nt = wv&1); 9 K-steps each
  {
    int nt = wv & 1, half = wv >> 1;
    f32x4 oa = {0.f, 0.f, 0.f, 0.f};
#pragma unroll
    for (int si = 0; si < 9; ++si) {
      int s2 = half * 9 + si;
      int tap = s2 >> 2, ks = s2 & 3;
      int kx = tap / 3, ky = tap % 3;
      bf16x8 a = *(const bf16x8*)&xnT[((h + kx) * 6 + (w + ky)) * 136 + ks * 32 + g * 8];
      bf16x8 bb = *(const bf16x8*)&wppk[((s2 * 2 + nt) * 64 + l) * 8];
      oa = __builtin_amdgcn_mfma_f32_16x16x32_bf16(a, bb, oa, 0, 0, 0);
    }
#pragma unroll
    for (int r = 0; r < 4; ++r) cscr[wv * 256 + (g * 4 + r) * 16 + px] = oa[r];
  }
  __syncthreads();
  // reduce partials -> offs ; zero sAT (xnT dead)
  if (t < 288) {
    int o = t >> 4, pp = t & 15;
    int nt = o >> 4, cc2 = o & 15;
    float v = bp[o];
#pragma unroll
    for (int half = 0; half < 4; ++half) v += cscr[(half * 2 + nt) * 256 + pp * 16 + cc2];
    offs[o * 16 + pp] = v;
  }
  __syncthreads();
  for (int i = t; i < 720; i += 512) ((uint4*)sAT)[i] = z;
  __syncthreads();
  // sampling -> scatter bilinear weights into S^T: sAT[(n*16+p)*40 + pix]
  if (t < 144) {
    int p = t / 9, n = t % 9;
    int hh = p >> 2, ww = p & 3;
    float sx = offs[n * 16 + p] + (float)(hh + 1) + (float)(n / 3 - 1);
    float sy = offs[(9 + n) * 16 + p] + (float)(ww + 1) + (float)(n % 3 - 1);
    float fx = floorf(sx), fy = floorf(sy);
    float qlx = fminf(fmaxf(fx, 0.f), 5.f);
    float qly = fminf(fmaxf(fy, 0.f), 5.f);
    float qrx = fminf(fmaxf(fx + 1.f, 0.f), 5.f);
    float qry = fminf(fmaxf(fy + 1.f, 0.f), 5.f);
    float pxc = fminf(fmaxf(sx, 0.f), 5.f);
    float pyc = fminf(fmaxf(sy, 0.f), 5.f);
    float glt = (1.f + (qlx - pxc)) * (1.f + (qly - pyc));
    float grb = (1.f - (qrx - pxc)) * (1.f - (qry - pyc));
    float glb = (1.f + (qlx - pxc)) * (1.f - (qry - pyc));
    float grt = (1.f - (qrx - pxc)) * (1.f + (qly - pyc));
    int ilx = (int)qlx, ily = (int)qly, irx = (int)qrx, iry = (int)qry;
    int rowb = (n * 16 + p) * 40;
    auto PUT = [&](int qx, int qy, float gv) {
      if (qx >= 1 && qx <= 4 && qy >= 1 && qy <= 4)
        sAT[rowb + (qx - 1) * 4 + (qy - 1)] = f2bf(gv);
    };
    PUT(ilx, ily, glt);
    PUT(irx, iry, grb);
    PUT(ilx, iry, glb);
    PUT(irx, ily, grt);
  }
  __syncthreads();
  // 2 phases x { issue bb prefetch; build 18 K-steps of xoffA; barrier; consume 18 MFMA }
  f32x4 acc = {0.f, 0.f, 0.f, 0.f};
  for (int ph = 0; ph < 2; ++ph) {
    bf16x8 bbq[6];
#pragma unroll
    for (int u = 0; u < 6; ++u)
      bbq[u] = *(const bf16x8*)&wdp[(((ph * 18 + u) * 8 + wv) * 64 + l) * 8];
    // build: tile m -> tt = ph*18 + m/2, q = tt&3, n = tt>>2, ct = 2q + (m&1)
    for (int m = wv; m < 36; m += 8) {
      int ttl = m >> 1;
      int tt = ph * 18 + ttl;
      int q = tt & 3, n = tt >> 2;
      int ct = 2 * q + (m & 1);
      bf16x8 a = *(const bf16x8*)&xnb2[(ct * 16 + cc) * 24 + g * 8];
      bf16x8 bS = *(const bf16x8*)&sAT[(n * 16 + cc) * 40 + g * 8];
      f32x4 d = __builtin_amdgcn_mfma_f32_16x16x32_bf16(a, bS, f32x4{0.f, 0.f, 0.f, 0.f}, 0, 0, 0);
      // lane (g,cc) holds xoff[ci = ct*16+g*4+r][n][px=cc] -> 4 consecutive j of slot (ttl, g'*16+cc)
      int gp2 = (ct & 1) * 2 + (g >> 1);
      unsigned lo = (unsigned)f2bf(d[0]) | ((unsigned)f2bf(d[1]) << 16);
      unsigned hi = (unsigned)f2bf(d[2]) | ((unsigned)f2bf(d[3]) << 16);
      *(uint2*)&xoffA[(ttl * 64 + gp2 * 16 + cc) * 8 + (g & 1) * 4] = (uint2){lo, hi};
    }
    __syncthreads();
#pragma unroll
    for (int ti = 0; ti < 18; ++ti) {
      bf16x8 a = *(const bf16x8*)&xoffA[(ti * 64 + l) * 8];
      acc = __builtin_amdgcn_mfma_f32_16x16x32_bf16(a, bbq[ti % 6], acc, 0, 0, 0);
      if (ti + 6 < 18)
        bbq[ti % 6] = *(const bf16x8*)&wdp[(((ph * 18 + ti + 6) * 8 + wv) * 64 + l) * 8];
    }
    __syncthreads();
  }
  // stage C (xnb2/sAT dead), then coalesced epilogue
  {
    int rg = l >> 4;
    int co = wv * 16 + cc;
#pragma unroll
    for (int r = 0; r < 4; ++r) ystg[co * 16 + rg * 4 + r] = acc[r];
  }
  __syncthreads();
  {
    int c = t >> 2, e0 = (t & 3) * 4;
    float s1 = 0.f, s2 = 0.f;
    float vr[4];
#pragma unroll
    for (int e = 0; e < 4; ++e) {
      float v = fmaxf(ystg[c * 16 + e0 + e], 0.f);
      vr[e] = v; s1 += v; s2 += v * v;
    }
    *(float4*)&y4[b * 2048 + c * 16 + e0] = make_float4(vr[0], vr[1], vr[2], vr[3]);
    atomicAdd(&sst[c], s1);
    atomicAdd(&sst[128 + c], s2);
  }
  __syncthreads();
  if (t < 256) atomicAdd(&stout[t], sst[t]);
}

// final: BN4-finalize folded + spatial mean + linear; 4 images per block
__global__ __launch_bounds__(256) void k_final(const float* __restrict__ y4,
                                               const float* __restrict__ stp,
                                               const float* __restrict__ gp,
                                               const float* __restrict__ bpar,
                                               const float* __restrict__ Wc, const float* __restrict__ bc,
                                               float* __restrict__ out) {
  __shared__ float vs[4][128];
  __shared__ float scS[256];
  int t = threadIdx.x, wv = t >> 6, l = t & 63;
  if (t < 128) {
    float m = stp[t] / CNT;
    float v = stp[128 + t] / CNT - m * m;
    float s = gp[t] * rsqrtf(fmaxf(v, 0.f) + 1e-5f);
    scS[t] = s; scS[128 + t] = bpar[t] - m * s;
  }
  __syncthreads();
  int img = blockIdx.x * 4 + wv;
  const float4* yp = (const float4*)(y4 + img * 2048);
  float4 a0 = yp[l * 8 + 0], a1 = yp[l * 8 + 1], a2 = yp[l * 8 + 2], a3 = yp[l * 8 + 3];
  float4 b0 = yp[l * 8 + 4], b1 = yp[l * 8 + 5], b2 = yp[l * 8 + 6], b3 = yp[l * 8 + 7];
  float s0 = (a0.x + a0.y + a0.z + a0.w) + (a1.x + a1.y + a1.z + a1.w) +
             (a2.x + a2.y + a2.z + a2.w) + (a3.x + a3.y + a3.z + a3.w);
  float s1 = (b0.x + b0.y + b0.z + b0.w) + (b1.x + b1.y + b1.z + b1.w) +
             (b2.x + b2.y + b2.z + b2.w) + (b3.x + b3.y + b3.z + b3.w);
  int c0 = l * 2, c1 = l * 2 + 1;
  vs[wv][c0] = scS[c0] * (s0 * 0.0625f) + scS[128 + c0];
  vs[wv][c1] = scS[c1] * (s1 * 0.0625f) + scS[128 + c1];
  __syncthreads();
  if (l < 40) {
    int o = l >> 2, q = l & 3;
    float p = 0.f;
    const float* wr = Wc + o * 128 + q * 32;
    const float* vr = &vs[wv][q * 32];
#pragma unroll
    for (int c = 0; c < 32; ++c) p += wr[c] * vr[c];
    p += __shfl_xor(p, 1);
    p += __shfl_xor(p, 2);
    if (q == 0) out[img * 10 + o] = p + bc[o];
  }
}

extern "C" void kernel_launch(void* const* d_in, const int* in_sizes, int n_in,
                              void* d_out, int out_size, void* d_ws, size_t ws_size,
                              hipStream_t stream) {
  const float* x  = (const float*)d_in[0];
  const float* W1 = (const float*)d_in[1];
  const float* g1 = (const float*)d_in[2];
  const float* b1 = (const float*)d_in[3];
  const float* W2 = (const float*)d_in[4];
  const float* g2 = (const float*)d_in[5];
  const float* b2 = (const float*)d_in[6];
  const float* W3 = (const float*)d_in[7];
  const float* g3 = (const float*)d_in[8];
  const float* b3 = (const float*)d_in[9];
  const float* Wp = (const float*)d_in[10];
  const float* bp = (const float*)d_in[11];
  const float* Wd = (const float*)d_in[12];
  const float* g4 = (const float*)d_in[13];
  const float* b4 = (const float*)d_in[14];
  const float* Wc = (const float*)d_in[15];
  const float* bc = (const float*)d_in[16];
  float* ws = (float*)d_ws;
  float* out = (float*)d_out;

  hipMemsetAsync(ws + OFF_ST, 0, 1024 * sizeof(float), stream);
  k_pre<<<782, 256, 0, stream>>>(W2, W3, Wp, Wd,
                                 (unsigned short*)(ws + OFF_W2P), (unsigned short*)(ws + OFF_W3P),
                                 (unsigned short*)(ws + OFF_WPP), (unsigned short*)(ws + OFF_WDP),
                                 x, W1, ws + OFF_Y1, ws + OFF_ST);
  k_convm<32, 64><<<NB / 2, 512, 0, stream>>>(ws + OFF_Y1, (const unsigned short*)(ws + OFF_W2P),
                                              ws + OFF_ST, g1, b1, ws + OFF_Y2, ws + OFF_ST + 256);
  k_convm<64, 128><<<NB / 2, 512, 0, stream>>>(ws + OFF_Y2, (const unsigned short*)(ws + OFF_W3P),
                                               ws + OFF_ST + 256, g2, b2, ws + OFF_Y3, ws + OFF_ST + 512);
  k_deform<<<NB, 512, 0, stream>>>(ws + OFF_Y3, (const unsigned short*)(ws + OFF_WPP), bp,
                                   (const unsigned short*)(ws + OFF_WDP),
                                   ws + OFF_ST + 512, g3, b3, ws + OFF_Y4, ws + OFF_ST + 768);
  k_final<<<512, 256, 0, stream>>>(ws + OFF_Y4, ws + OFF_ST + 768, g4, b4, Wc, bc, out);
}

// Round 10
// 146.887 us; speedup vs baseline: 1.3318x; 1.1461x over previous
//
#include <hip/hip_runtime.h>

#define NB 2048
#define CNT 32768.0f   // per-channel count = B*H*W = 2048*16

// workspace float offsets
#define OFF_Y1   0          // 2048*32*16
#define OFF_Y2   1048576    // 2048*64*16
#define OFF_Y3   3145728    // 2048*128*16
#define OFF_MEAN 7340032    // 2048*128 pooled channel sums (was y4)
#define OFF_ST   11534336   // 4 layers x 256
#define OFF_W2P  11536384   // conv2 pack: 18432 ushort
#define OFF_W3P  11545600   // conv3 pack: 73728 ushort
#define OFF_WPP  11582464   // offset-conv pack: 36864 ushort
#define OFF_WDP  11600896   // Wd pack: 147456 ushort

typedef __attribute__((ext_vector_type(8))) short bf16x8;
typedef __attribute__((ext_vector_type(4))) float f32x4;

__device__ __forceinline__ unsigned short f2bf(float f) {
  union { float f; unsigned int u; } v; v.f = f;
  unsigned int r = v.u + 0x7FFFu + ((v.u >> 16) & 1u);
  return (unsigned short)(r >> 16);
}

// pack conv weight [CO][CI][3][3] -> bf16 B-fragments, tap-major K (step = tap*KST+ks)
__device__ __forceinline__ void packw_one(const float* __restrict__ w, unsigned short* __restrict__ wpk,
                                          int CI, int CO, int NT, int i) {
  int KST = CI >> 5;
  int j = i & 7, l = (i >> 3) & 63, sn = i >> 9;
  int nt = sn % NT, step = sn / NT;
  int tap = step / KST, ks = step - tap * KST;
  int ci = ks * 32 + (l >> 4) * 8 + j, co = nt * 16 + (l & 15);
  wpk[i] = (co < CO) ? f2bf(w[(co * CI + ci) * 9 + tap]) : (unsigned short)0;
}

// pack Wd with K-order k = n*128 + ci  (n = tap index)
__device__ __forceinline__ void packwd_one(const float* __restrict__ Wd, unsigned short* __restrict__ wdp, int i) {
  int co = i / 1152, k = i % 1152;
  int n = k >> 7, ci = k & 127;
  int tt = k >> 5, kk = k & 31, g = kk >> 3, j = kk & 7;
  int nt = co >> 4, cc = co & 15, l = g * 16 + cc;
  wdp[((tt * 8 + nt) * 64 + l) * 8 + j] = f2bf(Wd[co * 1152 + ci * 9 + n]);
}

// merged: blocks [0,270) pack weights; blocks [270,782) conv1, 4 images each
__global__ __launch_bounds__(256) void k_pre(const float* __restrict__ W2, const float* __restrict__ W3,
                                             const float* __restrict__ Wp, const float* __restrict__ Wd,
                                             unsigned short* __restrict__ w2p, unsigned short* __restrict__ w3p,
                                             unsigned short* __restrict__ wpp, unsigned short* __restrict__ wdp,
                                             const float* __restrict__ x, const float* __restrict__ W1,
                                             float* __restrict__ y1, float* __restrict__ st) {
  __shared__ float xs[192];
  __shared__ float w1s[864];
  __shared__ float sst[64];
  int t = threadIdx.x;
  if (blockIdx.x < 270) {
#pragma unroll
    for (int ii = 0; ii < 4; ++ii) {
      int i = blockIdx.x * 1024 + ii * 256 + t;
      if (i < 18432) packw_one(W2, w2p, 32, 64, 4, i);
      else if (i < 92160) packw_one(W3, w3p, 64, 128, 8, i - 18432);
      else if (i < 129024) packw_one(Wp, wpp, 128, 18, 2, i - 92160);
      else if (i < 276480) packwd_one(Wd, wdp, i - 129024);
    }
    return;
  }
  int b0 = (blockIdx.x - 270) * 4;
  if (t < 192) xs[t] = x[b0 * 48 + t];
  for (int i = t; i < 864; i += 256) w1s[i] = W1[i];
  if (t < 64) sst[t] = 0.f;
  __syncthreads();
  for (int r = 0; r < 2; ++r) {
    int o = t + r * 256;
    int co = o >> 4, p = o & 15, h = p >> 2, w = p & 3;
    float s1 = 0.f, s2 = 0.f;
#pragma unroll
    for (int img = 0; img < 4; ++img) {
      float acc = 0.f;
      for (int ci = 0; ci < 3; ++ci) {
#pragma unroll
        for (int kx = 0; kx < 3; ++kx) {
          int ih = h + kx - 1;
          if (ih < 0 || ih > 3) continue;
#pragma unroll
          for (int ky = 0; ky < 3; ++ky) {
            int iw = w + ky - 1;
            if (iw < 0 || iw > 3) continue;
            acc += w1s[co * 27 + ci * 9 + kx * 3 + ky] * xs[img * 48 + ci * 16 + ih * 4 + iw];
          }
        }
      }
      acc = fmaxf(acc, 0.f);
      y1[(b0 + img) * 512 + o] = acc;
      s1 += acc; s2 += acc * acc;
    }
    atomicAdd(&sst[co], s1);
    atomicAdd(&sst[32 + co], s2);
  }
  __syncthreads();
  if (t < 64) atomicAdd(&st[(t < 32) ? t : (96 + t)], sst[t]);
}

// MFMA conv 3x3 pad1 over 4x4; 512 threads, 8 waves = (img, N-quarter); 2 images/block.
template <int CI, int CO>
__global__ __launch_bounds__(512, 4) void k_convm(const float* __restrict__ yin,
                                                  const unsigned short* __restrict__ wpk,
                                                  const float* __restrict__ stp,
                                                  const float* __restrict__ gp,
                                                  const float* __restrict__ bpar,
                                                  float* __restrict__ yout, float* __restrict__ stout) {
  constexpr int KST = CI / 32, NSTEP = 9 * KST, NT = CO / 16, TPW = NT / 4;
  constexpr int STR = 72;
  __shared__ __align__(16) unsigned short xnT[2][36 * STR];
  __shared__ float cst[2][CO * 16];
  __shared__ float scS[2 * CI];
  __shared__ float sst[2 * CO];
  int b0 = blockIdx.x * 2, t = threadIdx.x;
  uint4 z = {0u, 0u, 0u, 0u};
  for (int i = t; i < (2 * 36 * STR) / 8; i += 512) ((uint4*)xnT)[i] = z;
  if (t < CI) {
    float m = stp[t] / CNT;
    float v = stp[128 + t] / CNT - m * m;
    float s = gp[t] * rsqrtf(fmaxf(v, 0.f) + 1e-5f);
    scS[t] = s; scS[CI + t] = bpar[t] - m * s;
  }
  if (t < 2 * CO) sst[t] = 0.f;
  __syncthreads();
  for (int i = t; i < 2 * CI * 16; i += 512) {
    int img = i / (CI * 16), r = i - img * (CI * 16);
    int c = r >> 4, p = r & 15, h = p >> 2, w = p & 3;
    float v = yin[(b0 + img) * CI * 16 + r] * scS[c] + scS[CI + c];
    xnT[img][((h + 1) * 6 + (w + 1)) * STR + c] = f2bf(v);
  }
  __syncthreads();
  int wv = t >> 6, l = t & 63, px = l & 15, g = l >> 4;
  int h = px >> 2, w = px & 3;
  int img = wv >> 2, wq = wv & 3;
  f32x4 acc[TPW];
#pragma unroll
  for (int tw = 0; tw < TPW; ++tw) acc[tw] = f32x4{0.f, 0.f, 0.f, 0.f};
#pragma unroll
  for (int step = 0; step < NSTEP; ++step) {
    int tap = step / KST, ks = step - tap * KST;
    int kx = tap / 3, ky = tap % 3;
    bf16x8 a = *(const bf16x8*)&xnT[img][((h + kx) * 6 + (w + ky)) * STR + ks * 32 + g * 8];
#pragma unroll
    for (int tw = 0; tw < TPW; ++tw) {
      int nt = wq * TPW + tw;
      bf16x8 bb = *(const bf16x8*)&wpk[((step * NT + nt) * 64 + l) * 8];
      acc[tw] = __builtin_amdgcn_mfma_f32_16x16x32_bf16(a, bb, acc[tw], 0, 0, 0);
    }
  }
  int cc = l & 15;
#pragma unroll
  for (int tw = 0; tw < TPW; ++tw) {
    int co = (wq * TPW + tw) * 16 + cc;
#pragma unroll
    for (int r = 0; r < 4; ++r) cst[img][co * 16 + (g * 4 + r)] = acc[tw][r];
  }
  __syncthreads();
  {
    constexpr int EPT = CO / 16;
    constexpr int TPC = 256 / CO;
    int ime = t >> 8, tl = t & 255;
    int c = tl / TPC, e0 = (tl % TPC) * EPT;
    float s1 = 0.f, s2 = 0.f;
    float vr[EPT];
#pragma unroll
    for (int e = 0; e < EPT; ++e) {
      float v = fmaxf(cst[ime][c * 16 + e0 + e], 0.f);
      vr[e] = v; s1 += v; s2 += v * v;
    }
#pragma unroll
    for (int e = 0; e < EPT; e += 4)
      *(float4*)&yout[(b0 + ime) * CO * 16 + c * 16 + e0 + e] = make_float4(vr[e], vr[e + 1], vr[e + 2], vr[e + 3]);
    atomicAdd(&sst[c], s1);
    atomicAdd(&sst[CO + c], s2);
  }
  __syncthreads();
  if (t < 2 * CO) atomicAdd(&stout[(t < CO) ? t : (128 - CO + t)], sst[t]);
}

// deformable conv: 2 images/block, shared-B consume (2 acc chains), pooled-mean output (no y4).
// LDS 76544 B -> 2 blocks/CU.
__global__ __launch_bounds__(512, 4) void k_deform(const float* __restrict__ y3,
                                                   const unsigned short* __restrict__ wppk,
                                                   const float* __restrict__ bp,
                                                   const unsigned short* __restrict__ wdp,
                                                   const float* __restrict__ stp,
                                                   const float* __restrict__ gp,
                                                   const float* __restrict__ bpar,
                                                   float* __restrict__ meanw, float* __restrict__ stout) {
  __shared__ __align__(16) unsigned char smem[76544];
  unsigned short* xnb2 = (unsigned short*)smem;             // [0,12288) 2 x 128x24 ush [img][ci][pix]
  unsigned short* xnT  = (unsigned short*)(smem + 12288);   // [12288,31872) 2 x 36x136 (offset conv)
  unsigned short* sAT  = (unsigned short*)(smem + 12288);   // overlay: 2 x 9x16x40 ush (23040B)
  float* cscr = (float*)(smem + 35328);                     // overlay in R3: 8x256 f32 partials
  unsigned short* xoffA = (unsigned short*)(smem + 35328);  // [35328,72192) 2 x 18x512 ush per phase
  float* offs = (float*)(smem + 72192);                     // 2 x 288 f32
  float* scS  = (float*)(smem + 74496);                     // 256 f32
  float* sst  = (float*)(smem + 75520);                     // 256 f32
  int b0 = blockIdx.x * 2, t = threadIdx.x;
  uint4 z = {0u, 0u, 0u, 0u};
  for (int i = t; i < 1992; i += 512) ((uint4*)smem)[i] = z;  // zero xnb2 + xnT
  if (t < 128) {
    float m = stp[t] / CNT;
    float v = stp[128 + t] / CNT - m * m;
    float s = gp[t] * rsqrtf(fmaxf(v, 0.f) + 1e-5f);
    scS[t] = s; scS[128 + t] = bpar[t] - m * s;
  }
  if (t < 256) sst[t] = 0.f;
  __syncthreads();
  for (int i = t; i < 4096; i += 512) {
    int img = i >> 11, r = i & 2047;
    int c = r >> 4, p = r & 15, h = p >> 2, w = p & 3;
    float v = y3[(b0 + img) * 2048 + r] * scS[c] + scS[128 + c];
    unsigned short bv = f2bf(v);
    xnb2[img * 3072 + c * 24 + p] = bv;
    xnT[img * 4896 + ((h + 1) * 6 + (w + 1)) * 136 + c] = bv;
  }
  __syncthreads();
  int wv = t >> 6, l = t & 63, px = l & 15, g = l >> 4, cc = l & 15;
  int h = px >> 2, w = px & 3;
  // offset conv via MFMA: wave = (img = wv>>2, half = (wv>>1)&1, nt = wv&1); 18 K-steps each
  {
    int imo = wv >> 2, half = (wv >> 1) & 1, nt = wv & 1;
    f32x4 oa = {0.f, 0.f, 0.f, 0.f};
#pragma unroll
    for (int si = 0; si < 18; ++si) {
      int s2 = half * 18 + si;
      int tap = s2 >> 2, ks = s2 & 3;
      int kx = tap / 3, ky = tap % 3;
      bf16x8 a = *(const bf16x8*)&xnT[imo * 4896 + ((h + kx) * 6 + (w + ky)) * 136 + ks * 32 + g * 8];
      bf16x8 bb = *(const bf16x8*)&wppk[((s2 * 2 + nt) * 64 + l) * 8];
      oa = __builtin_amdgcn_mfma_f32_16x16x32_bf16(a, bb, oa, 0, 0, 0);
    }
#pragma unroll
    for (int r = 0; r < 4; ++r) cscr[wv * 256 + (g * 4 + r) * 16 + px] = oa[r];
  }
  __syncthreads();
  // reduce partials -> offs[img]; then zero sAT (xnT dead)
  for (int i = t; i < 576; i += 512) {
    int imo = i / 288, r = i - imo * 288;
    int o = r >> 4, pp = r & 15;
    int nt = o >> 4, cc2 = o & 15;
    float v = bp[o] + cscr[(imo * 4 + nt) * 256 + pp * 16 + cc2]
            + cscr[(imo * 4 + 2 + nt) * 256 + pp * 16 + cc2];
    offs[imo * 288 + o * 16 + pp] = v;
  }
  __syncthreads();
  for (int i = t; i < 1440; i += 512) ((uint4*)(smem + 12288))[i] = z;  // zero sAT
  __syncthreads();
  // sampling -> scatter bilinear weights into S^T per image
  if (t < 288) {
    int imo = t / 144, r = t - imo * 144;
    int p = r / 9, n = r % 9;
    int hh = p >> 2, ww = p & 3;
    float sx = offs[imo * 288 + n * 16 + p] + (float)(hh + 1) + (float)(n / 3 - 1);
    float sy = offs[imo * 288 + (9 + n) * 16 + p] + (float)(ww + 1) + (float)(n % 3 - 1);
    float fx = floorf(sx), fy = floorf(sy);
    float qlx = fminf(fmaxf(fx, 0.f), 5.f);
    float qly = fminf(fmaxf(fy, 0.f), 5.f);
    float qrx = fminf(fmaxf(fx + 1.f, 0.f), 5.f);
    float qry = fminf(fmaxf(fy + 1.f, 0.f), 5.f);
    float pxc = fminf(fmaxf(sx, 0.f), 5.f);
    float pyc = fminf(fmaxf(sy, 0.f), 5.f);
    float glt = (1.f + (qlx - pxc)) * (1.f + (qly - pyc));
    float grb = (1.f - (qrx - pxc)) * (1.f - (qry - pyc));
    float glb = (1.f + (qlx - pxc)) * (1.f - (qry - pyc));
    float grt = (1.f - (qrx - pxc)) * (1.f + (qly - pyc));
    int ilx = (int)qlx, ily = (int)qly, irx = (int)qrx, iry = (int)qry;
    int rowb = imo * 5760 + (n * 16 + p) * 40;
    auto PUT = [&](int qx, int qy, float gv) {
      if (qx >= 1 && qx <= 4 && qy >= 1 && qy <= 4)
        sAT[rowb + (qx - 1) * 4 + (qy - 1)] = f2bf(gv);
    };
    PUT(ilx, ily, glt);
    PUT(irx, iry, grb);
    PUT(ilx, iry, glb);
    PUT(irx, ily, grt);
  }
  __syncthreads();
  // 2 phases x { build 2x18 K-steps of xoffA; barrier; consume 18 K-steps x 2 images }
  f32x4 acc0 = {0.f, 0.f, 0.f, 0.f};
  f32x4 acc1 = {0.f, 0.f, 0.f, 0.f};
  for (int ph = 0; ph < 2; ++ph) {
    for (int m = wv; m < 72; m += 8) {
      int imo = m / 36, mm = m - imo * 36;
      int ttl = mm >> 1;
      int tt = ph * 18 + ttl;
      int q = tt & 3, n = tt >> 2;
      int ct = 2 * q + (mm & 1);
      bf16x8 a = *(const bf16x8*)&xnb2[imo * 3072 + (ct * 16 + cc) * 24 + g * 8];
      bf16x8 bS = *(const bf16x8*)&sAT[imo * 5760 + (n * 16 + cc) * 40 + g * 8];
      f32x4 d = __builtin_amdgcn_mfma_f32_16x16x32_bf16(a, bS, f32x4{0.f, 0.f, 0.f, 0.f}, 0, 0, 0);
      int gp2 = (ct & 1) * 2 + (g >> 1);
      unsigned lo = (unsigned)f2bf(d[0]) | ((unsigned)f2bf(d[1]) << 16);
      unsigned hi = (unsigned)f2bf(d[2]) | ((unsigned)f2bf(d[3]) << 16);
      *(uint2*)&xoffA[imo * 9216 + (ttl * 64 + gp2 * 16 + cc) * 8 + (g & 1) * 4] = (uint2){lo, hi};
    }
    __syncthreads();
#pragma unroll
    for (int ti = 0; ti < 18; ++ti) {
      bf16x8 bb = *(const bf16x8*)&wdp[(((ph * 18 + ti) * 8 + wv) * 64 + l) * 8];
      bf16x8 a0 = *(const bf16x8*)&xoffA[(ti * 64 + l) * 8];
      bf16x8 a1 = *(const bf16x8*)&xoffA[9216 + (ti * 64 + l) * 8];
      acc0 = __builtin_amdgcn_mfma_f32_16x16x32_bf16(a0, bb, acc0, 0, 0, 0);
      acc1 = __builtin_amdgcn_mfma_f32_16x16x32_bf16(a1, bb, acc1, 0, 0, 0);
    }
    __syncthreads();
  }
  // epilogue: relu + in-register pooled sums (shfl over g-lanes) + stats; no y4
  {
    float s1a = 0.f, s2a = 0.f, s1b = 0.f, s2b = 0.f;
#pragma unroll
    for (int r = 0; r < 4; ++r) {
      float v0 = fmaxf(acc0[r], 0.f);
      float v1 = fmaxf(acc1[r], 0.f);
      s1a += v0; s2a += v0 * v0;
      s1b += v1; s2b += v1 * v1;
    }
    s1a += __shfl_xor(s1a, 16); s1a += __shfl_xor(s1a, 32);
    s2a += __shfl_xor(s2a, 16); s2a += __shfl_xor(s2a, 32);
    s1b += __shfl_xor(s1b, 16); s1b += __shfl_xor(s1b, 32);
    s2b += __shfl_xor(s2b, 16); s2b += __shfl_xor(s2b, 32);
    if (g == 0) {
      int co = wv * 16 + cc;
      meanw[b0 * 128 + co] = s1a;
      meanw[(b0 + 1) * 128 + co] = s1b;
      atomicAdd(&sst[co], s1a + s1b);
      atomicAdd(&sst[128 + co], s2a + s2b);
    }
  }
  __syncthreads();
  if (t < 256) atomicAdd(&stout[t], sst[t]);
}

// final: BN4 fold + linear on pooled sums. 80 blocks x 256 thr, thread = (img, o).
__global__ __launch_bounds__(256) void k_final(const float* __restrict__ mean,
                                               const float* __restrict__ stp,
                                               const float* __restrict__ gp,
                                               const float* __restrict__ bpar,
                                               const float* __restrict__ Wc, const float* __restrict__ bc,
                                               float* __restrict__ out) {
  __shared__ float wf[1280];
  __shared__ float scS[256];
  __shared__ float tb[10];
  int t = threadIdx.x;
  if (t < 128) {
    float m = stp[t] / CNT;
    float v = stp[128 + t] / CNT - m * m;
    float s = gp[t] * rsqrtf(fmaxf(v, 0.f) + 1e-5f);
    scS[t] = s; scS[128 + t] = bpar[t] - m * s;
  }
  __syncthreads();
  for (int i = t; i < 1280; i += 256) {
    int c = i & 127;
    wf[i] = Wc[i] * scS[c] * 0.0625f;
  }
  __syncthreads();
  if (t < 10) {
    float s = bc[t];
    for (int c = 0; c < 128; ++c) s += Wc[t * 128 + c] * scS[128 + c];
    tb[t] = s;
  }
  __syncthreads();
  int gidx = blockIdx.x * 256 + t;
  int img = gidx / 10, o = gidx - img * 10;
  const float* mr = mean + img * 128;
  const float* wr = wf + o * 128;
  float acc = tb[o];
#pragma unroll 8
  for (int c = 0; c < 128; ++c) acc += wr[c] * mr[c];
  out[gidx] = acc;
}

extern "C" void kernel_launch(void* const* d_in, const int* in_sizes, int n_in,
                              void* d_out, int out_size, void* d_ws, size_t ws_size,
                              hipStream_t stream) {
  const float* x  = (const float*)d_in[0];
  const float* W1 = (const float*)d_in[1];
  const float* g1 = (const float*)d_in[2];
  const float* b1 = (const float*)d_in[3];
  const float* W2 = (const float*)d_in[4];
  const float* g2 = (const float*)d_in[5];
  const float* b2 = (const float*)d_in[6];
  const float* W3 = (const float*)d_in[7];
  const float* g3 = (const float*)d_in[8];
  const float* b3 = (const float*)d_in[9];
  const float* Wp = (const float*)d_in[10];
  const float* bp = (const float*)d_in[11];
  const float* Wd = (const float*)d_in[12];
  const float* g4 = (const float*)d_in[13];
  const float* b4 = (const float*)d_in[14];
  const float* Wc = (const float*)d_in[15];
  const float* bc = (const float*)d_in[16];
  float* ws = (float*)d_ws;
  float* out = (float*)d_out;

  hipMemsetAsync(ws + OFF_ST, 0, 1024 * sizeof(float), stream);
  k_pre<<<782, 256, 0, stream>>>(W2, W3, Wp, Wd,
                                 (unsigned short*)(ws + OFF_W2P), (unsigned short*)(ws + OFF_W3P),
                                 (unsigned short*)(ws + OFF_WPP), (unsigned short*)(ws + OFF_WDP),
                                 x, W1, ws + OFF_Y1, ws + OFF_ST);
  k_convm<32, 64><<<NB / 2, 512, 0, stream>>>(ws + OFF_Y1, (const unsigned short*)(ws + OFF_W2P),
                                              ws + OFF_ST, g1, b1, ws + OFF_Y2, ws + OFF_ST + 256);
  k_convm<64, 128><<<NB / 2, 512, 0, stream>>>(ws + OFF_Y2, (const unsigned short*)(ws + OFF_W3P),
                                               ws + OFF_ST + 256, g2, b2, ws + OFF_Y3, ws + OFF_ST + 512);
  k_deform<<<NB / 2, 512, 0, stream>>>(ws + OFF_Y3, (const unsigned short*)(ws + OFF_WPP), bp,
                                       (const unsigned short*)(ws + OFF_WDP),
                                       ws + OFF_ST + 512, g3, b3, ws + OFF_MEAN, ws + OFF_ST + 768);
  k_final<<<80, 256, 0, stream>>>(ws + OFF_MEAN, ws + OFF_ST + 768, g4, b4, Wc, bc, out);
}

// Round 11
// 124.631 us; speedup vs baseline: 1.5696x; 1.1786x over previous
//
#include <hip/hip_runtime.h>

#define NB 2048
#define CNT 32768.0f   // per-channel count = B*H*W = 2048*16

// workspace float offsets (activations are bf16/ushort now)
#define OFF_Y1   0          // 2048*512 ush = 524288 f
#define OFF_Y2   524288     // 2048*1024 ush = 1048576 f
#define OFF_Y3   1572864    // 2048*2048 ush = 2097152 f
#define OFF_MEAN 3670016    // 2048*128 f pooled channel sums
#define OFF_ST   3932160    // 4 layers x 256 f
#define OFF_W2P  3933184    // 18432 ush
#define OFF_W3P  3942400    // 73728 ush
#define OFF_WPP  3979264    // 36864 ush
#define OFF_WDP  3997696    // 147456 ush

typedef __attribute__((ext_vector_type(8))) short bf16x8;
typedef __attribute__((ext_vector_type(4))) float f32x4;

__device__ __forceinline__ unsigned short f2bf(float f) {
  union { float f; unsigned int u; } v; v.f = f;
  unsigned int r = v.u + 0x7FFFu + ((v.u >> 16) & 1u);
  return (unsigned short)(r >> 16);
}
__device__ __forceinline__ float bf2f(unsigned short u) {
  union { unsigned int u; float f; } v; v.u = ((unsigned int)u) << 16;
  return v.f;
}

// pack conv weight [CO][CI][3][3] -> bf16 B-fragments, tap-major K (step = tap*KST+ks)
__device__ __forceinline__ void packw_one(const float* __restrict__ w, unsigned short* __restrict__ wpk,
                                          int CI, int CO, int NT, int i) {
  int KST = CI >> 5;
  int j = i & 7, l = (i >> 3) & 63, sn = i >> 9;
  int nt = sn % NT, step = sn / NT;
  int tap = step / KST, ks = step - tap * KST;
  int ci = ks * 32 + (l >> 4) * 8 + j, co = nt * 16 + (l & 15);
  wpk[i] = (co < CO) ? f2bf(w[(co * CI + ci) * 9 + tap]) : (unsigned short)0;
}

// pack Wd with K-order k = n*128 + ci  (n = tap index)
__device__ __forceinline__ void packwd_one(const float* __restrict__ Wd, unsigned short* __restrict__ wdp, int i) {
  int co = i / 1152, k = i % 1152;
  int n = k >> 7, ci = k & 127;
  int tt = k >> 5, kk = k & 31, g = kk >> 3, j = kk & 7;
  int nt = co >> 4, cc = co & 15, l = g * 16 + cc;
  wdp[((tt * 8 + nt) * 64 + l) * 8 + j] = f2bf(Wd[co * 1152 + ci * 9 + n]);
}

// merged: blocks [0,270) pack weights; blocks [270,782) conv1, 4 images each
__global__ __launch_bounds__(256) void k_pre(const float* __restrict__ W2, const float* __restrict__ W3,
                                             const float* __restrict__ Wp, const float* __restrict__ Wd,
                                             unsigned short* __restrict__ w2p, unsigned short* __restrict__ w3p,
                                             unsigned short* __restrict__ wpp, unsigned short* __restrict__ wdp,
                                             const float* __restrict__ x, const float* __restrict__ W1,
                                             unsigned short* __restrict__ y1, float* __restrict__ st) {
  __shared__ float xs[192];
  __shared__ float w1s[864];
  __shared__ float sst[64];
  int t = threadIdx.x;
  if (blockIdx.x < 270) {
#pragma unroll
    for (int ii = 0; ii < 4; ++ii) {
      int i = blockIdx.x * 1024 + ii * 256 + t;
      if (i < 18432) packw_one(W2, w2p, 32, 64, 4, i);
      else if (i < 92160) packw_one(W3, w3p, 64, 128, 8, i - 18432);
      else if (i < 129024) packw_one(Wp, wpp, 128, 18, 2, i - 92160);
      else if (i < 276480) packwd_one(Wd, wdp, i - 129024);
    }
    return;
  }
  int b0 = (blockIdx.x - 270) * 4;
  if (t < 192) xs[t] = x[b0 * 48 + t];
  for (int i = t; i < 864; i += 256) w1s[i] = W1[i];
  if (t < 64) sst[t] = 0.f;
  __syncthreads();
  for (int r = 0; r < 2; ++r) {
    int o = t + r * 256;
    int co = o >> 4, p = o & 15, h = p >> 2, w = p & 3;
    float s1 = 0.f, s2 = 0.f;
#pragma unroll
    for (int img = 0; img < 4; ++img) {
      float acc = 0.f;
      for (int ci = 0; ci < 3; ++ci) {
#pragma unroll
        for (int kx = 0; kx < 3; ++kx) {
          int ih = h + kx - 1;
          if (ih < 0 || ih > 3) continue;
#pragma unroll
          for (int ky = 0; ky < 3; ++ky) {
            int iw = w + ky - 1;
            if (iw < 0 || iw > 3) continue;
            acc += w1s[co * 27 + ci * 9 + kx * 3 + ky] * xs[img * 48 + ci * 16 + ih * 4 + iw];
          }
        }
      }
      acc = fmaxf(acc, 0.f);
      y1[(b0 + img) * 512 + o] = f2bf(acc);
      s1 += acc; s2 += acc * acc;
    }
    atomicAdd(&sst[co], s1);
    atomicAdd(&sst[32 + co], s2);
  }
  __syncthreads();
  if (t < 64) atomicAdd(&st[(t < 32) ? t : (96 + t)], sst[t]);
}

// MFMA conv 3x3 pad1 over 4x4; 4 images/block, 512 thr.
// conv3 (CO=128): wave = N-tile, 4 acc chains sharing each B-load (72 MFMA/wave).
// conv2 (CO=64): wave = (img-pair, N-quarter), 2 chains (18 MFMA/wave).
template <int CI, int CO>
__global__ __launch_bounds__(512, 4) void k_convm(const unsigned short* __restrict__ yin,
                                                  const unsigned short* __restrict__ wpk,
                                                  const float* __restrict__ stp,
                                                  const float* __restrict__ gp,
                                                  const float* __restrict__ bpar,
                                                  unsigned short* __restrict__ yout, float* __restrict__ stout) {
  constexpr int KST = CI / 32, NSTEP = 9 * KST, NT = CO / 16;
  constexpr int STR = (CI == 64) ? 72 : 40;
  constexpr int IPW = (CO == 128) ? 4 : 2;
  __shared__ __align__(16) unsigned short xnT[4][36 * STR];
  __shared__ float cst[2][CO * 16];
  __shared__ float scS[2 * CI];
  __shared__ float sst[2 * CO];
  int b0 = blockIdx.x * 4, t = threadIdx.x;
  uint4 z = {0u, 0u, 0u, 0u};
  for (int i = t; i < (4 * 36 * STR) / 8; i += 512) ((uint4*)xnT)[i] = z;
  if (t < CI) {
    float m = stp[t] / CNT;
    float v = stp[128 + t] / CNT - m * m;
    float s = gp[t] * rsqrtf(fmaxf(v, 0.f) + 1e-5f);
    scS[t] = s; scS[CI + t] = bpar[t] - m * s;
  }
  if (t < 2 * CO) sst[t] = 0.f;
  __syncthreads();
  for (int i = t; i < 4 * CI * 16; i += 512) {
    int img = i / (CI * 16), r = i - img * (CI * 16);
    int c = r >> 4, p = r & 15, h = p >> 2, w = p & 3;
    float v = bf2f(yin[(b0 + img) * CI * 16 + r]) * scS[c] + scS[CI + c];
    xnT[img][((h + 1) * 6 + (w + 1)) * STR + c] = f2bf(v);
  }
  __syncthreads();
  int wv = t >> 6, l = t & 63, px = l & 15, g = l >> 4, cc = l & 15;
  int h = px >> 2, w = px & 3;
  int wq = (CO == 128) ? wv : (wv & 3);
  int ib = (CO == 128) ? 0 : ((wv >> 2) * 2);
  f32x4 acc[IPW];
#pragma unroll
  for (int e = 0; e < IPW; ++e) acc[e] = f32x4{0.f, 0.f, 0.f, 0.f};
#pragma unroll
  for (int step = 0; step < NSTEP; ++step) {
    int tap = step / KST, ks = step - tap * KST;
    int kx = tap / 3, ky = tap % 3;
    bf16x8 bb = *(const bf16x8*)&wpk[((step * NT + wq) * 64 + l) * 8];
    int woff = ((h + kx) * 6 + (w + ky)) * STR + ks * 32 + g * 8;
#pragma unroll
    for (int e = 0; e < IPW; ++e) {
      bf16x8 a = *(const bf16x8*)&xnT[ib + e][woff];
      acc[e] = __builtin_amdgcn_mfma_f32_16x16x32_bf16(a, bb, acc[e], 0, 0, 0);
    }
  }
  // epilogue: 2 image-pair passes through cst
  constexpr int EPT = CO / 16;        // values per thread (8 or 4)
  constexpr int TPC = 256 / CO;       // threads per channel per image (2 or 4)
#pragma unroll
  for (int p = 0; p < 2; ++p) {
    if (CO == 128 || (wv >> 2) == p) {
#pragma unroll
      for (int e = 0; e < 2; ++e) {
        int src = (CO == 128) ? (2 * p + e) : e;
        int co = wq * 16 + cc;
#pragma unroll
        for (int r = 0; r < 4; ++r) cst[e][co * 16 + (g * 4 + r)] = acc[src][r];
      }
    }
    __syncthreads();
    {
      int ime = t >> 8, tl = t & 255;
      int c = tl / TPC, e0 = (tl % TPC) * EPT;
      float s1 = 0.f, s2 = 0.f;
      union { unsigned short u16[8]; uint4 u4; uint2 u2; } pk;
#pragma unroll
      for (int e = 0; e < EPT; ++e) {
        float v = fmaxf(cst[ime][c * 16 + e0 + e], 0.f);
        pk.u16[e] = f2bf(v);
        s1 += v; s2 += v * v;
      }
      unsigned short* dst = &yout[(b0 + 2 * p + ime) * CO * 16 + c * 16 + e0];
      if (EPT == 8) *(uint4*)dst = pk.u4; else *(uint2*)dst = pk.u2;
      atomicAdd(&sst[c], s1);
      atomicAdd(&sst[CO + c], s2);
    }
    __syncthreads();
  }
  if (t < 2 * CO) atomicAdd(&stout[(t < CO) ? t : (128 - CO + t)], sst[t]);
}

// deformable conv: 2 images/block, shared-B consume, pooled-mean output. (R10-proven, bf16 y3 in)
__global__ __launch_bounds__(512, 4) void k_deform(const unsigned short* __restrict__ y3,
                                                   const unsigned short* __restrict__ wppk,
                                                   const float* __restrict__ bp,
                                                   const unsigned short* __restrict__ wdp,
                                                   const float* __restrict__ stp,
                                                   const float* __restrict__ gp,
                                                   const float* __restrict__ bpar,
                                                   float* __restrict__ meanw, float* __restrict__ stout) {
  __shared__ __align__(16) unsigned char smem[76544];
  unsigned short* xnb2 = (unsigned short*)smem;             // [0,12288) 2 x 128x24
  unsigned short* xnT  = (unsigned short*)(smem + 12288);   // [12288,31872) 2 x 36x136
  unsigned short* sAT  = (unsigned short*)(smem + 12288);   // overlay: 2 x 9x16x40
  float* cscr = (float*)(smem + 35328);                     // overlay: 8x256 partials
  unsigned short* xoffA = (unsigned short*)(smem + 35328);  // 2 x 18x512 per phase
  float* offs = (float*)(smem + 72192);                     // 2 x 288
  float* scS  = (float*)(smem + 74496);                     // 256
  float* sst  = (float*)(smem + 75520);                     // 256
  int b0 = blockIdx.x * 2, t = threadIdx.x;
  uint4 z = {0u, 0u, 0u, 0u};
  for (int i = t; i < 1992; i += 512) ((uint4*)smem)[i] = z;
  if (t < 128) {
    float m = stp[t] / CNT;
    float v = stp[128 + t] / CNT - m * m;
    float s = gp[t] * rsqrtf(fmaxf(v, 0.f) + 1e-5f);
    scS[t] = s; scS[128 + t] = bpar[t] - m * s;
  }
  if (t < 256) sst[t] = 0.f;
  __syncthreads();
  for (int i = t; i < 4096; i += 512) {
    int img = i >> 11, r = i & 2047;
    int c = r >> 4, p = r & 15, h = p >> 2, w = p & 3;
    float v = bf2f(y3[(b0 + img) * 2048 + r]) * scS[c] + scS[128 + c];
    unsigned short bv = f2bf(v);
    xnb2[img * 3072 + c * 24 + p] = bv;
    xnT[img * 4896 + ((h + 1) * 6 + (w + 1)) * 136 + c] = bv;
  }
  __syncthreads();
  int wv = t >> 6, l = t & 63, px = l & 15, g = l >> 4, cc = l & 15;
  int h = px >> 2, w = px & 3;
  {
    int imo = wv >> 2, half = (wv >> 1) & 1, nt = wv & 1;
    f32x4 oa = {0.f, 0.f, 0.f, 0.f};
#pragma unroll
    for (int si = 0; si < 18; ++si) {
      int s2 = half * 18 + si;
      int tap = s2 >> 2, ks = s2 & 3;
      int kx = tap / 3, ky = tap % 3;
      bf16x8 a = *(const bf16x8*)&xnT[imo * 4896 + ((h + kx) * 6 + (w + ky)) * 136 + ks * 32 + g * 8];
      bf16x8 bb = *(const bf16x8*)&wppk[((s2 * 2 + nt) * 64 + l) * 8];
      oa = __builtin_amdgcn_mfma_f32_16x16x32_bf16(a, bb, oa, 0, 0, 0);
    }
#pragma unroll
    for (int r = 0; r < 4; ++r) cscr[wv * 256 + (g * 4 + r) * 16 + px] = oa[r];
  }
  __syncthreads();
  for (int i = t; i < 576; i += 512) {
    int imo = i / 288, r = i - imo * 288;
    int o = r >> 4, pp = r & 15;
    int nt = o >> 4, cc2 = o & 15;
    float v = bp[o] + cscr[(imo * 4 + nt) * 256 + pp * 16 + cc2]
            + cscr[(imo * 4 + 2 + nt) * 256 + pp * 16 + cc2];
    offs[imo * 288 + o * 16 + pp] = v;
  }
  __syncthreads();
  for (int i = t; i < 1440; i += 512) ((uint4*)(smem + 12288))[i] = z;
  __syncthreads();
  if (t < 288) {
    int imo = t / 144, r = t - imo * 144;
    int p = r / 9, n = r % 9;
    int hh = p >> 2, ww = p & 3;
    float sx = offs[imo * 288 + n * 16 + p] + (float)(hh + 1) + (float)(n / 3 - 1);
    float sy = offs[imo * 288 + (9 + n) * 16 + p] + (float)(ww + 1) + (float)(n % 3 - 1);
    float fx = floorf(sx), fy = floorf(sy);
    float qlx = fminf(fmaxf(fx, 0.f), 5.f);
    float qly = fminf(fmaxf(fy, 0.f), 5.f);
    float qrx = fminf(fmaxf(fx + 1.f, 0.f), 5.f);
    float qry = fminf(fmaxf(fy + 1.f, 0.f), 5.f);
    float pxc = fminf(fmaxf(sx, 0.f), 5.f);
    float pyc = fminf(fmaxf(sy, 0.f), 5.f);
    float glt = (1.f + (qlx - pxc)) * (1.f + (qly - pyc));
    float grb = (1.f - (qrx - pxc)) * (1.f - (qry - pyc));
    float glb = (1.f + (qlx - pxc)) * (1.f - (qry - pyc));
    float grt = (1.f - (qrx - pxc)) * (1.f + (qly - pyc));
    int ilx = (int)qlx, ily = (int)qly, irx = (int)qrx, iry = (int)qry;
    int rowb = imo * 5760 + (n * 16 + p) * 40;
    auto PUT = [&](int qx, int qy, float gv) {
      if (qx >= 1 && qx <= 4 && qy >= 1 && qy <= 4)
        sAT[rowb + (qx - 1) * 4 + (qy - 1)] = f2bf(gv);
    };
    PUT(ilx, ily, glt);
    PUT(irx, iry, grb);
    PUT(ilx, iry, glb);
    PUT(irx, ily, grt);
  }
  __syncthreads();
  f32x4 acc0 = {0.f, 0.f, 0.f, 0.f};
  f32x4 acc1 = {0.f, 0.f, 0.f, 0.f};
  for (int ph = 0; ph < 2; ++ph) {
    for (int m = wv; m < 72; m += 8) {
      int imo = m / 36, mm = m - imo * 36;
      int ttl = mm >> 1;
      int tt = ph * 18 + ttl;
      int q = tt & 3, n = tt >> 2;
      int ct = 2 * q + (mm & 1);
      bf16x8 a = *(const bf16x8*)&xnb2[imo * 3072 + (ct * 16 + cc) * 24 + g * 8];
      bf16x8 bS = *(const bf16x8*)&sAT[imo * 5760 + (n * 16 + cc) * 40 + g * 8];
      f32x4 d = __builtin_amdgcn_mfma_f32_16x16x32_bf16(a, bS, f32x4{0.f, 0.f, 0.f, 0.f}, 0, 0, 0);
      int gp2 = (ct & 1) * 2 + (g >> 1);
      unsigned lo = (unsigned)f2bf(d[0]) | ((unsigned)f2bf(d[1]) << 16);
      unsigned hi = (unsigned)f2bf(d[2]) | ((unsigned)f2bf(d[3]) << 16);
      *(uint2*)&xoffA[imo * 9216 + (ttl * 64 + gp2 * 16 + cc) * 8 + (g & 1) * 4] = (uint2){lo, hi};
    }
    __syncthreads();
#pragma unroll
    for (int ti = 0; ti < 18; ++ti) {
      bf16x8 bb = *(const bf16x8*)&wdp[(((ph * 18 + ti) * 8 + wv) * 64 + l) * 8];
      bf16x8 a0 = *(const bf16x8*)&xoffA[(ti * 64 + l) * 8];
      bf16x8 a1 = *(const bf16x8*)&xoffA[9216 + (ti * 64 + l) * 8];
      acc0 = __builtin_amdgcn_mfma_f32_16x16x32_bf16(a0, bb, acc0, 0, 0, 0);
      acc1 = __builtin_amdgcn_mfma_f32_16x16x32_bf16(a1, bb, acc1, 0, 0, 0);
    }
    __syncthreads();
  }
  {
    float s1a = 0.f, s2a = 0.f, s1b = 0.f, s2b = 0.f;
#pragma unroll
    for (int r = 0; r < 4; ++r) {
      float v0 = fmaxf(acc0[r], 0.f);
      float v1 = fmaxf(acc1[r], 0.f);
      s1a += v0; s2a += v0 * v0;
      s1b += v1; s2b += v1 * v1;
    }
    s1a += __shfl_xor(s1a, 16); s1a += __shfl_xor(s1a, 32);
    s2a += __shfl_xor(s2a, 16); s2a += __shfl_xor(s2a, 32);
    s1b += __shfl_xor(s1b, 16); s1b += __shfl_xor(s1b, 32);
    s2b += __shfl_xor(s2b, 16); s2b += __shfl_xor(s2b, 32);
    if (g == 0) {
      int co = wv * 16 + cc;
      meanw[b0 * 128 + co] = s1a;
      meanw[(b0 + 1) * 128 + co] = s1b;
      atomicAdd(&sst[co], s1a + s1b);
      atomicAdd(&sst[128 + co], s2a + s2b);
    }
  }
  __syncthreads();
  if (t < 256) atomicAdd(&stout[t], sst[t]);
}

// final: BN4 fold + linear on pooled sums. 80 blocks x 256 thr, thread = (img, o).
__global__ __launch_bounds__(256) void k_final(const float* __restrict__ mean,
                                               const float* __restrict__ stp,
                                               const float* __restrict__ gp,
                                               const float* __restrict__ bpar,
                                               const float* __restrict__ Wc, const float* __restrict__ bc,
                                               float* __restrict__ out) {
  __shared__ float wf[1280];
  __shared__ float scS[256];
  __shared__ float tb[10];
  int t = threadIdx.x;
  if (t < 128) {
    float m = stp[t] / CNT;
    float v = stp[128 + t] / CNT - m * m;
    float s = gp[t] * rsqrtf(fmaxf(v, 0.f) + 1e-5f);
    scS[t] = s; scS[128 + t] = bpar[t] - m * s;
  }
  __syncthreads();
  for (int i = t; i < 1280; i += 256) {
    int c = i & 127;
    wf[i] = Wc[i] * scS[c] * 0.0625f;
  }
  __syncthreads();
  if (t < 10) {
    float s = bc[t];
    for (int c = 0; c < 128; ++c) s += Wc[t * 128 + c] * scS[128 + c];
    tb[t] = s;
  }
  __syncthreads();
  int gidx = blockIdx.x * 256 + t;
  int img = gidx / 10, o = gidx - img * 10;
  const float* mr = mean + img * 128;
  const float* wr = wf + o * 128;
  float acc = tb[o];
#pragma unroll 8
  for (int c = 0; c < 128; ++c) acc += wr[c] * mr[c];
  out[gidx] = acc;
}

extern "C" void kernel_launch(void* const* d_in, const int* in_sizes, int n_in,
                              void* d_out, int out_size, void* d_ws, size_t ws_size,
                              hipStream_t stream) {
  const float* x  = (const float*)d_in[0];
  const float* W1 = (const float*)d_in[1];
  const float* g1 = (const float*)d_in[2];
  const float* b1 = (const float*)d_in[3];
  const float* W2 = (const float*)d_in[4];
  const float* g2 = (const float*)d_in[5];
  const float* b2 = (const float*)d_in[6];
  const float* W3 = (const float*)d_in[7];
  const float* g3 = (const float*)d_in[8];
  const float* b3 = (const float*)d_in[9];
  const float* Wp = (const float*)d_in[10];
  const float* bp = (const float*)d_in[11];
  const float* Wd = (const float*)d_in[12];
  const float* g4 = (const float*)d_in[13];
  const float* b4 = (const float*)d_in[14];
  const float* Wc = (const float*)d_in[15];
  const float* bc = (const float*)d_in[16];
  float* ws = (float*)d_ws;
  float* out = (float*)d_out;

  hipMemsetAsync(ws + OFF_ST, 0, 1024 * sizeof(float), stream);
  k_pre<<<782, 256, 0, stream>>>(W2, W3, Wp, Wd,
                                 (unsigned short*)(ws + OFF_W2P), (unsigned short*)(ws + OFF_W3P),
                                 (unsigned short*)(ws + OFF_WPP), (unsigned short*)(ws + OFF_WDP),
                                 x, W1, (unsigned short*)(ws + OFF_Y1), ws + OFF_ST);
  k_convm<32, 64><<<NB / 4, 512, 0, stream>>>((const unsigned short*)(ws + OFF_Y1),
                                              (const unsigned short*)(ws + OFF_W2P),
                                              ws + OFF_ST, g1, b1,
                                              (unsigned short*)(ws + OFF_Y2), ws + OFF_ST + 256);
  k_convm<64, 128><<<NB / 4, 512, 0, stream>>>((const unsigned short*)(ws + OFF_Y2),
                                               (const unsigned short*)(ws + OFF_W3P),
                                               ws + OFF_ST + 256, g2, b2,
                                               (unsigned short*)(ws + OFF_Y3), ws + OFF_ST + 512);
  k_deform<<<NB / 2, 512, 0, stream>>>((const unsigned short*)(ws + OFF_Y3),
                                       (const unsigned short*)(ws + OFF_WPP), bp,
                                       (const unsigned short*)(ws + OFF_WDP),
                                       ws + OFF_ST + 512, g3, b3, ws + OFF_MEAN, ws + OFF_ST + 768);
  k_final<<<80, 256, 0, stream>>>(ws + OFF_MEAN, ws + OFF_ST + 768, g4, b4, Wc, bc, out);
}